// Round 1
// baseline (7548.582 us; speedup 1.0000x reference)
//
#include <hip/hip_runtime.h>

#define D 128
#define BN_EPS 1e-5f

// ---------------------------------------------------------------------------
// edge-attr combo table: 9 combos (a0 in 0..2, a1 in 0..2) + self-loop (4,0)
// etbl[combo*128 + c], combo 9 = self-loop vector
__global__ __launch_bounds__(256) void k_etbl(const float* __restrict__ e1,
                                              const float* __restrict__ e2,
                                              float* __restrict__ etbl) {
  int idx = blockIdx.x * 256 + threadIdx.x;
  if (idx < 9 * D) {
    int combo = idx / D, c = idx % D;
    int a0 = combo / 3, a1 = combo % 3;
    etbl[idx] = e1[a0 * D + c] + e2[a1 * D + c];
  } else if (idx < 10 * D) {
    int c = idx - 9 * D;
    etbl[idx] = e1[4 * D + c] + e2[c];
  }
}

// node embedding: h = x_emb1[x[:,0]] + x_emb2[x[:,1]]
__global__ __launch_bounds__(256) void k_embed(const int* __restrict__ x,
                                               const float* __restrict__ emb1,
                                               const float* __restrict__ emb2,
                                               float* __restrict__ out, int n) {
  int idx = blockIdx.x * 256 + threadIdx.x;
  if (idx >= n * (D / 4)) return;
  int node = idx >> 5, c4 = idx & 31;
  int i1 = x[2 * node], i2 = x[2 * node + 1];
  float4 v1 = *(const float4*)(emb1 + (size_t)i1 * D + c4 * 4);
  float4 v2 = *(const float4*)(emb2 + (size_t)i2 * D + c4 * 4);
  float4 o;
  o.x = v1.x + v2.x; o.y = v1.y + v2.y; o.z = v1.z + v2.z; o.w = v1.w + v2.w;
  *(float4*)(out + (size_t)node * D + c4 * 4) = o;
}

// init aggregation buffers (self-loop contributions folded in):
//   z1   = 2.1*h1 + e_self   (GIN: edges + selfloop(h1+es) + (1+eps)*h1)
//   a030 = h0 + e_self
//   a021 = 0, a110 = 0
__global__ __launch_bounds__(256) void k_init(const float* __restrict__ h0,
                                              const float* __restrict__ h1,
                                              const float* __restrict__ etbl,
                                              float* __restrict__ z1,
                                              float* __restrict__ a021,
                                              float* __restrict__ a110,
                                              float* __restrict__ a030,
                                              int n0, int n1) {
  int idx = blockIdx.x * 256 + threadIdx.x;
  int i = idx >> 5, c4 = idx & 31;
  float4 es = *(const float4*)(etbl + 9 * D + c4 * 4);
  float4 zero = make_float4(0.f, 0.f, 0.f, 0.f);
  if (i < n1) {
    float4 h = *(const float4*)(h1 + (size_t)i * D + c4 * 4);
    float4 z;
    z.x = 2.1f * h.x + es.x; z.y = 2.1f * h.y + es.y;
    z.z = 2.1f * h.z + es.z; z.w = 2.1f * h.w + es.w;
    *(float4*)(z1 + (size_t)i * D + c4 * 4) = z;
    *(float4*)(a021 + (size_t)i * D + c4 * 4) = zero;
  }
  if (i < n0) {
    float4 h = *(const float4*)(h0 + (size_t)i * D + c4 * 4);
    float4 z;
    z.x = h.x + es.x; z.y = h.y + es.y; z.z = h.z + es.z; z.w = h.w + es.w;
    *(float4*)(a030 + (size_t)i * D + c4 * 4) = z;
    *(float4*)(a110 + (size_t)i * D + c4 * 4) = zero;
  }
}

// edge scatter: agg[dst] += hsrc[src] + etbl[a0*3+a1]
// 32 lanes per edge, float4 per lane, 4 atomicAdds
__global__ __launch_bounds__(256) void k_scatter(const float* __restrict__ hsrc,
                                                 const int* __restrict__ ei,
                                                 const int* __restrict__ ea,
                                                 const float* __restrict__ etbl,
                                                 float* __restrict__ agg, int E) {
  int t = blockIdx.x * 256 + threadIdx.x;
  int e = t >> 5;
  if (e >= E) return;
  int l = t & 31;
  int src = ei[e], dst = ei[E + e];
  int a0 = ea[2 * e], a1 = ea[2 * e + 1];
  float4 h = *(const float4*)(hsrc + (size_t)src * D + l * 4);
  float4 ev = *(const float4*)(etbl + (size_t)(a0 * 3 + a1) * D + l * 4);
  float* p = agg + (size_t)dst * D + l * 4;
  atomicAdd(p + 0, h.x + ev.x);
  atomicAdd(p + 1, h.y + ev.y);
  atomicAdd(p + 2, h.z + ev.z);
  atomicAdd(p + 3, h.w + ev.w);
}

// ---------------------------------------------------------------------------
// fused fp32 GEMM: C = s1*(A1@W1) + s2*(A2@W2) + s1*bias1 + s2*bias2, opt ReLU
// A row-major [M][K], W row-major [K][NCOLS]. K multiple of 32.
// Block tile: BM x NCOLS, thread tile 8x8, 256 threads.
template <int NCOLS, bool RELU, bool TWO>
__global__ __launch_bounds__(256) void gemm_fused(
    const float* __restrict__ A1, int K1, const float* __restrict__ W1,
    const float* __restrict__ A2, int K2, const float* __restrict__ W2,
    const float* __restrict__ bias1, const float* __restrict__ bias2,
    float s1, float s2, float* __restrict__ C, int M) {
  constexpr int CG = NCOLS / 8;    // column groups of 8
  constexpr int BM = 2048 / CG;    // 128 (NCOLS=128) or 64 (NCOLS=256)
  constexpr int BMP = BM + 4;      // pad, keeps 16B alignment
  __shared__ float As[32 * BMP];   // transposed: As[kk*BMP + row]
  __shared__ float Ws[32 * NCOLS]; // Ws[kk*NCOLS + col]

  int tid = threadIdx.x;
  int tx = tid % CG;  // col group
  int ty = tid / CG;  // row group (8 rows)
  int row0 = blockIdx.x * BM;

  float acc[8][8];
#pragma unroll
  for (int r = 0; r < 8; ++r)
#pragma unroll
    for (int c = 0; c < 8; ++c) acc[r][c] = 0.f;

  float rel = TWO ? (s2 / s1) : 0.f;

  for (int srci = 0; srci < (TWO ? 2 : 1); ++srci) {
    const float* A = srci ? A2 : A1;
    const float* W = srci ? W2 : W1;
    int K = srci ? K2 : K1;
    float ls = srci ? rel : 1.0f;
    for (int k0 = 0; k0 < K; k0 += 32) {
      __syncthreads();
      // stage A chunk (BM x 32) transposed into LDS
      constexpr int AF4 = BM / 32;  // float4s per thread
#pragma unroll
      for (int p = 0; p < AF4; ++p) {
        int f = p * 256 + tid;
        int r = f >> 3;
        int c4 = f & 7;
        float4 v = make_float4(0.f, 0.f, 0.f, 0.f);
        int gr = row0 + r;
        if (gr < M) v = *(const float4*)(A + (size_t)gr * K + k0 + c4 * 4);
        int kk = c4 * 4;
        As[(kk + 0) * BMP + r] = v.x * ls;
        As[(kk + 1) * BMP + r] = v.y * ls;
        As[(kk + 2) * BMP + r] = v.z * ls;
        As[(kk + 3) * BMP + r] = v.w * ls;
      }
      // stage W chunk (32 x NCOLS)
      constexpr int WF4 = NCOLS / 32;  // float4s per thread
#pragma unroll
      for (int p = 0; p < WF4; ++p) {
        int f = p * 256 + tid;
        int r = f / (NCOLS / 4);
        int c4 = f % (NCOLS / 4);
        *(float4*)(Ws + r * NCOLS + c4 * 4) =
            *(const float4*)(W + (size_t)(k0 + r) * NCOLS + c4 * 4);
      }
      __syncthreads();
#pragma unroll
      for (int kk = 0; kk < 32; ++kk) {
        float a[8], w[8];
        *(float4*)(a) = *(float4*)(As + kk * BMP + ty * 8);
        *(float4*)(a + 4) = *(float4*)(As + kk * BMP + ty * 8 + 4);
        *(float4*)(w) = *(float4*)(Ws + kk * NCOLS + tx * 8);
        *(float4*)(w + 4) = *(float4*)(Ws + kk * NCOLS + tx * 8 + 4);
#pragma unroll
        for (int r = 0; r < 8; ++r)
#pragma unroll
          for (int c = 0; c < 8; ++c) acc[r][c] += a[r] * w[c];
      }
    }
  }

  int colb = tx * 8;
  float bv[8];
#pragma unroll
  for (int c = 0; c < 8; ++c) {
    float b = bias1[colb + c] * s1;
    if (TWO) b += bias2[colb + c] * s2;
    bv[c] = b;
  }
#pragma unroll
  for (int r = 0; r < 8; ++r) {
    int gr = row0 + ty * 8 + r;
    if (gr >= M) continue;
    float ov[8];
#pragma unroll
    for (int c = 0; c < 8; ++c) {
      float v = acc[r][c] * s1 + bv[c];
      if (RELU) v = fmaxf(v, 0.f);
      ov[c] = v;
    }
    *(float4*)(C + (size_t)gr * NCOLS + colb) = *(float4*)(ov);
    *(float4*)(C + (size_t)gr * NCOLS + colb + 4) = *(float4*)(ov + 4);
  }
}

// ---------------------------------------------------------------------------
// per-column sum and sum-of-squares (for batch-norm statistics)
__global__ __launch_bounds__(128) void k_colsum(const float* __restrict__ X,
                                                int M, float* __restrict__ st) {
  int d = threadIdx.x;
  int r0 = blockIdx.x * 512;
  int r1 = min(r0 + 512, M);
  float s = 0.f, q = 0.f;
  for (int r = r0; r < r1; ++r) {
    float v = X[(size_t)r * D + d];
    s += v;
    q += v * v;
  }
  atomicAdd(&st[d], s);
  atomicAdd(&st[D + d], q);
}

// batch-norm normalize (in place) + optional ReLU
template <bool RELU>
__global__ __launch_bounds__(256) void k_bn(float* __restrict__ X, int M,
                                            const float* __restrict__ st,
                                            const float* __restrict__ gamma,
                                            const float* __restrict__ beta,
                                            float invM) {
  int idx = blockIdx.x * 256 + threadIdx.x;
  int i = idx >> 5, c4 = idx & 31;
  if (i >= M) return;
  float4 v = *(float4*)(X + (size_t)i * D + c4 * 4);
  float vv[4] = {v.x, v.y, v.z, v.w};
  float o[4];
#pragma unroll
  for (int j = 0; j < 4; ++j) {
    int d = c4 * 4 + j;
    float mu = st[d] * invM;
    float var = st[D + d] * invM - mu * mu;
    float sc = rsqrtf(var + BN_EPS) * gamma[d];
    float sh = beta[d] - mu * sc;
    float x = vv[j] * sc + sh;
    if (RELU) x = fmaxf(x, 0.f);
    o[j] = x;
  }
  *(float4*)(X + (size_t)i * D + c4 * 4) = *(float4*)o;
}

// ---------------------------------------------------------------------------
extern "C" void kernel_launch(void* const* d_in, const int* in_sizes, int n_in,
                              void* d_out, int out_size, void* d_ws,
                              size_t ws_size, hipStream_t stream) {
  const int* x0 = (const int*)d_in[0];
  const int* x1 = (const int*)d_in[1];
  const int* ei101 = (const int*)d_in[2];
  const int* ea101 = (const int*)d_in[3];
  const int* ei110 = (const int*)d_in[4];
  const int* ea110 = (const int*)d_in[5];
  const int* ei021 = (const int*)d_in[6];
  const int* ea021 = (const int*)d_in[7];
  const int* ei030 = (const int*)d_in[8];
  const int* ea030 = (const int*)d_in[9];
  const float* x_emb1 = (const float*)d_in[10];
  const float* x_emb2 = (const float*)d_in[11];
  const float* e_emb1 = (const float*)d_in[12];
  const float* e_emb2 = (const float*)d_in[13];
  const float* gin_w1 = (const float*)d_in[14];
  const float* gin_b1 = (const float*)d_in[15];
  const float* gin_w2 = (const float*)d_in[16];
  const float* gin_b2 = (const float*)d_in[17];
  const float* w110 = (const float*)d_in[18];
  const float* b110 = (const float*)d_in[19];
  const float* w021 = (const float*)d_in[20];
  const float* b021 = (const float*)d_in[21];
  const float* w030 = (const float*)d_in[22];
  const float* b030 = (const float*)d_in[23];
  const float* bn_gamma = (const float*)d_in[24];
  const float* bn_beta = (const float*)d_in[25];

  int n0 = in_sizes[0] / 2, n1 = in_sizes[1] / 2;
  int E = in_sizes[2] / 2;

  float* h0 = (float*)d_out;
  float* h1 = h0 + (size_t)n0 * D;

  float* ws = (float*)d_ws;
  float* z1 = ws;                         // n1*D
  float* a021 = z1 + (size_t)n1 * D;      // n1*D
  float* a110 = a021 + (size_t)n1 * D;    // n0*D
  float* a030 = a110 + (size_t)n0 * D;    // n0*D
  float* etbl = a030 + (size_t)n0 * D;    // 10*D
  float* stats = etbl + 10 * D;           // 4*D (stats0 | stats1)
  float* hidden = a110;  // alias: n1*2D fits in a110+a030 (n1 <= n0)

  dim3 b256(256);
  k_etbl<<<5, b256, 0, stream>>>(e_emb1, e_emb2, etbl);
  k_embed<<<(n0 * 32 + 255) / 256, b256, 0, stream>>>(x0, x_emb1, x_emb2, h0, n0);
  k_embed<<<(n1 * 32 + 255) / 256, b256, 0, stream>>>(x1, x_emb1, x_emb2, h1, n1);

  int nmax = n0 > n1 ? n0 : n1;
  int scatterBlocks = (E * 32 + 255) / 256;

  for (int layer = 0; layer < 3; ++layer) {
    k_init<<<(nmax * 32 + 255) / 256, b256, 0, stream>>>(h0, h1, etbl, z1, a021,
                                                         a110, a030, n0, n1);
    k_scatter<<<scatterBlocks, b256, 0, stream>>>(h1, ei101, ea101, etbl, z1, E);
    k_scatter<<<scatterBlocks, b256, 0, stream>>>(h0, ei021, ea021, etbl, a021, E);
    k_scatter<<<scatterBlocks, b256, 0, stream>>>(h1, ei110, ea110, etbl, a110, E);
    k_scatter<<<scatterBlocks, b256, 0, stream>>>(h0, ei030, ea030, etbl, a030, E);

    // out0 = 0.05*(a110@w110 + a030@w030 + b110 + b030)  -> h0 region
    gemm_fused<128, false, true><<<(n0 + 127) / 128, b256, 0, stream>>>(
        a110, 128, w110, a030, 128, w030, b110, b030, 0.05f, 0.05f, h0, n0);
    // hidden = relu(z1 @ gin_w1 + gin_b1)   (overwrites a110/a030 region)
    gemm_fused<256, true, false><<<(n1 + 63) / 64, b256, 0, stream>>>(
        z1, 128, gin_w1, nullptr, 0, nullptr, gin_b1, nullptr, 1.0f, 0.0f,
        hidden, n1);
    // out1 = 0.5*(hidden@gin_w2 + gin_b2) + 0.05*(a021@w021 + b021) -> h1
    gemm_fused<128, false, true><<<(n1 + 127) / 128, b256, 0, stream>>>(
        hidden, 256, gin_w2, a021, 128, w021, gin_b2, b021, 0.5f, 0.05f, h1, n1);

    hipMemsetAsync(stats, 0, 4 * D * sizeof(float), stream);
    k_colsum<<<(n0 + 511) / 512, dim3(128), 0, stream>>>(h0, n0, stats);
    k_colsum<<<(n1 + 511) / 512, dim3(128), 0, stream>>>(h1, n1, stats + 2 * D);

    const float* g = bn_gamma + layer * D;
    const float* bb = bn_beta + layer * D;
    if (layer < 2) {
      k_bn<true><<<(n0 * 32 + 255) / 256, b256, 0, stream>>>(h0, n0, stats, g, bb, 1.0f / n0);
      k_bn<true><<<(n1 * 32 + 255) / 256, b256, 0, stream>>>(h1, n1, stats + 2 * D, g, bb, 1.0f / n1);
    } else {
      k_bn<false><<<(n0 * 32 + 255) / 256, b256, 0, stream>>>(h0, n0, stats, g, bb, 1.0f / n0);
      k_bn<false><<<(n1 * 32 + 255) / 256, b256, 0, stream>>>(h1, n1, stats + 2 * D, g, bb, 1.0f / n1);
    }
  }
}

// Round 2
// 2364.621 us; speedup vs baseline: 3.1923x; 3.1923x over previous
//
#include <hip/hip_runtime.h>

#define D 128
#define BN_EPS 1e-5f

// ---------------------------------------------------------------------------
// edge-attr combo table: 9 combos (a0 in 0..2, a1 in 0..2) + self-loop (4,0)
__global__ __launch_bounds__(256) void k_etbl(const float* __restrict__ e1,
                                              const float* __restrict__ e2,
                                              float* __restrict__ etbl) {
  int idx = blockIdx.x * 256 + threadIdx.x;
  if (idx < 9 * D) {
    int combo = idx / D, c = idx % D;
    int a0 = combo / 3, a1 = combo % 3;
    etbl[idx] = e1[a0 * D + c] + e2[a1 * D + c];
  } else if (idx < 10 * D) {
    int c = idx - 9 * D;
    etbl[idx] = e1[4 * D + c] + e2[c];
  }
}

// node embedding: h = x_emb1[x[:,0]] + x_emb2[x[:,1]]
__global__ __launch_bounds__(256) void k_embed(const int* __restrict__ x,
                                               const float* __restrict__ emb1,
                                               const float* __restrict__ emb2,
                                               float* __restrict__ out, int n) {
  int idx = blockIdx.x * 256 + threadIdx.x;
  if (idx >= n * (D / 4)) return;
  int node = idx >> 5, c4 = idx & 31;
  int i1 = x[2 * node], i2 = x[2 * node + 1];
  float4 v1 = *(const float4*)(emb1 + (size_t)i1 * D + c4 * 4);
  float4 v2 = *(const float4*)(emb2 + (size_t)i2 * D + c4 * 4);
  float4 o;
  o.x = v1.x + v2.x; o.y = v1.y + v2.y; o.z = v1.z + v2.z; o.w = v1.w + v2.w;
  *(float4*)(out + (size_t)node * D + c4 * 4) = o;
}

// ---------------------------------------------------------------------------
// CSR build: histogram -> single-block scan -> fill
__global__ __launch_bounds__(256) void k_hist(const int* __restrict__ ei,
                                              int* __restrict__ cursor, int E) {
  int e = blockIdx.x * 256 + threadIdx.x;
  if (e >= E) return;
  atomicAdd(&cursor[ei[E + e]], 1);
}

__global__ __launch_bounds__(1024) void k_scan(int* __restrict__ cursor,
                                               int* __restrict__ rowptr, int n,
                                               int E) {
  __shared__ int lds[1024];
  int tid = threadIdx.x;
  int chunk = (n + 1023) >> 10;
  int b = tid * chunk;
  int e = min(b + chunk, n);
  int s = 0;
  for (int i = b; i < e; ++i) s += cursor[i];
  lds[tid] = s;
  __syncthreads();
  for (int off = 1; off < 1024; off <<= 1) {
    int v = (tid >= off) ? lds[tid - off] : 0;
    __syncthreads();
    lds[tid] += v;
    __syncthreads();
  }
  int run = (tid == 0) ? 0 : lds[tid - 1];
  for (int i = b; i < e; ++i) {
    int d = cursor[i];
    rowptr[i] = run;
    cursor[i] = run;  // cursor becomes the fill position
    run += d;
  }
  if (tid == 1023) rowptr[n] = E;
}

// payload = src | (combo << 16)   (src < 65536, combo < 9)
__global__ __launch_bounds__(256) void k_fill(const int* __restrict__ ei,
                                              const int* __restrict__ ea,
                                              int* __restrict__ cursor,
                                              int* __restrict__ payload, int E) {
  int e = blockIdx.x * 256 + threadIdx.x;
  if (e >= E) return;
  int dst = ei[E + e];
  int src = ei[e];
  int combo = ea[2 * e] * 3 + ea[2 * e + 1];
  int pos = atomicAdd(&cursor[dst], 1);
  payload[pos] = src | (combo << 16);
}

// ---------------------------------------------------------------------------
// CSR gather: agg[g] = init(g) + sum_{e in edges(g)} (hsrc[src_e] + etbl[combo_e])
// MODE 0: init = 0;  MODE 1: init = hinit[g] + es;  MODE 2: init = 2.1*hinit[g] + es
template <int MODE>
__global__ __launch_bounds__(256) void k_gather(
    const float* __restrict__ hsrc, const float* __restrict__ hinit,
    const int* __restrict__ rowptr, const int* __restrict__ payload,
    const float* __restrict__ etbl, float* __restrict__ agg, int n) {
  __shared__ float et[10 * D];
  for (int i = threadIdx.x; i < 10 * D; i += 256) et[i] = etbl[i];
  __syncthreads();
  int g = blockIdx.x * 8 + (threadIdx.x >> 5);
  if (g >= n) return;
  int c = (threadIdx.x & 31) * 4;
  float4 acc;
  if (MODE == 0) {
    acc = make_float4(0.f, 0.f, 0.f, 0.f);
  } else {
    float4 h = *(const float4*)(hinit + (size_t)g * D + c);
    float4 es = *(const float4*)(et + 9 * D + c);
    float sc = (MODE == 2) ? 2.1f : 1.0f;
    acc.x = sc * h.x + es.x; acc.y = sc * h.y + es.y;
    acc.z = sc * h.z + es.z; acc.w = sc * h.w + es.w;
  }
  int e0 = rowptr[g], e1 = rowptr[g + 1];
  for (int e = e0; e < e1; ++e) {
    int p = payload[e];
    int src = p & 0xFFFF;
    int combo = p >> 16;
    float4 h = *(const float4*)(hsrc + (size_t)src * D + c);
    float4 ev = *(const float4*)(et + combo * D + c);
    acc.x += h.x + ev.x; acc.y += h.y + ev.y;
    acc.z += h.z + ev.z; acc.w += h.w + ev.w;
  }
  *(float4*)(agg + (size_t)g * D + c) = acc;
}

// ---------------------------------------------------------------------------
// fused fp32 GEMM: C = s1*(A1@W1) + s2*(A2@W2) + s1*bias1 + s2*bias2, opt ReLU
template <int NCOLS, bool RELU, bool TWO>
__global__ __launch_bounds__(256) void gemm_fused(
    const float* __restrict__ A1, int K1, const float* __restrict__ W1,
    const float* __restrict__ A2, int K2, const float* __restrict__ W2,
    const float* __restrict__ bias1, const float* __restrict__ bias2,
    float s1, float s2, float* __restrict__ C, int M) {
  constexpr int CG = NCOLS / 8;
  constexpr int BM = 2048 / CG;
  constexpr int BMP = BM + 4;
  __shared__ float As[32 * BMP];
  __shared__ float Ws[32 * NCOLS];

  int tid = threadIdx.x;
  int tx = tid % CG;
  int ty = tid / CG;
  int row0 = blockIdx.x * BM;

  float acc[8][8];
#pragma unroll
  for (int r = 0; r < 8; ++r)
#pragma unroll
    for (int c = 0; c < 8; ++c) acc[r][c] = 0.f;

  float rel = TWO ? (s2 / s1) : 0.f;

  for (int srci = 0; srci < (TWO ? 2 : 1); ++srci) {
    const float* A = srci ? A2 : A1;
    const float* W = srci ? W2 : W1;
    int K = srci ? K2 : K1;
    float ls = srci ? rel : 1.0f;
    for (int k0 = 0; k0 < K; k0 += 32) {
      __syncthreads();
      constexpr int AF4 = BM / 32;
#pragma unroll
      for (int p = 0; p < AF4; ++p) {
        int f = p * 256 + tid;
        int r = f >> 3;
        int c4 = f & 7;
        float4 v = make_float4(0.f, 0.f, 0.f, 0.f);
        int gr = row0 + r;
        if (gr < M) v = *(const float4*)(A + (size_t)gr * K + k0 + c4 * 4);
        int kk = c4 * 4;
        As[(kk + 0) * BMP + r] = v.x * ls;
        As[(kk + 1) * BMP + r] = v.y * ls;
        As[(kk + 2) * BMP + r] = v.z * ls;
        As[(kk + 3) * BMP + r] = v.w * ls;
      }
      constexpr int WF4 = NCOLS / 32;
#pragma unroll
      for (int p = 0; p < WF4; ++p) {
        int f = p * 256 + tid;
        int r = f / (NCOLS / 4);
        int c4 = f % (NCOLS / 4);
        *(float4*)(Ws + r * NCOLS + c4 * 4) =
            *(const float4*)(W + (size_t)(k0 + r) * NCOLS + c4 * 4);
      }
      __syncthreads();
#pragma unroll
      for (int kk = 0; kk < 32; ++kk) {
        float a[8], w[8];
        *(float4*)(a) = *(float4*)(As + kk * BMP + ty * 8);
        *(float4*)(a + 4) = *(float4*)(As + kk * BMP + ty * 8 + 4);
        *(float4*)(w) = *(float4*)(Ws + kk * NCOLS + tx * 8);
        *(float4*)(w + 4) = *(float4*)(Ws + kk * NCOLS + tx * 8 + 4);
#pragma unroll
        for (int r = 0; r < 8; ++r)
#pragma unroll
          for (int c = 0; c < 8; ++c) acc[r][c] += a[r] * w[c];
      }
    }
  }

  int colb = tx * 8;
  float bv[8];
#pragma unroll
  for (int c = 0; c < 8; ++c) {
    float b = bias1[colb + c] * s1;
    if (TWO) b += bias2[colb + c] * s2;
    bv[c] = b;
  }
#pragma unroll
  for (int r = 0; r < 8; ++r) {
    int gr = row0 + ty * 8 + r;
    if (gr >= M) continue;
    float ov[8];
#pragma unroll
    for (int c = 0; c < 8; ++c) {
      float v = acc[r][c] * s1 + bv[c];
      if (RELU) v = fmaxf(v, 0.f);
      ov[c] = v;
    }
    *(float4*)(C + (size_t)gr * NCOLS + colb) = *(float4*)(ov);
    *(float4*)(C + (size_t)gr * NCOLS + colb + 4) = *(float4*)(ov + 4);
  }
}

// ---------------------------------------------------------------------------
__global__ __launch_bounds__(128) void k_colsum(const float* __restrict__ X,
                                                int M, float* __restrict__ st) {
  int d = threadIdx.x;
  int r0 = blockIdx.x * 512;
  int r1 = min(r0 + 512, M);
  float s = 0.f, q = 0.f;
  for (int r = r0; r < r1; ++r) {
    float v = X[(size_t)r * D + d];
    s += v;
    q += v * v;
  }
  atomicAdd(&st[d], s);
  atomicAdd(&st[D + d], q);
}

template <bool RELU>
__global__ __launch_bounds__(256) void k_bn(float* __restrict__ X, int M,
                                            const float* __restrict__ st,
                                            const float* __restrict__ gamma,
                                            const float* __restrict__ beta,
                                            float invM) {
  int idx = blockIdx.x * 256 + threadIdx.x;
  int i = idx >> 5, c4 = idx & 31;
  if (i >= M) return;
  float4 v = *(float4*)(X + (size_t)i * D + c4 * 4);
  float vv[4] = {v.x, v.y, v.z, v.w};
  float o[4];
#pragma unroll
  for (int j = 0; j < 4; ++j) {
    int d = c4 * 4 + j;
    float mu = st[d] * invM;
    float var = st[D + d] * invM - mu * mu;
    float sc = rsqrtf(var + BN_EPS) * gamma[d];
    float sh = beta[d] - mu * sc;
    float x = vv[j] * sc + sh;
    if (RELU) x = fmaxf(x, 0.f);
    o[j] = x;
  }
  *(float4*)(X + (size_t)i * D + c4 * 4) = *(float4*)o;
}

// ---------------------------------------------------------------------------
extern "C" void kernel_launch(void* const* d_in, const int* in_sizes, int n_in,
                              void* d_out, int out_size, void* d_ws,
                              size_t ws_size, hipStream_t stream) {
  const int* x0 = (const int*)d_in[0];
  const int* x1 = (const int*)d_in[1];
  const int* ei101 = (const int*)d_in[2];
  const int* ea101 = (const int*)d_in[3];
  const int* ei110 = (const int*)d_in[4];
  const int* ea110 = (const int*)d_in[5];
  const int* ei021 = (const int*)d_in[6];
  const int* ea021 = (const int*)d_in[7];
  const int* ei030 = (const int*)d_in[8];
  const int* ea030 = (const int*)d_in[9];
  const float* x_emb1 = (const float*)d_in[10];
  const float* x_emb2 = (const float*)d_in[11];
  const float* e_emb1 = (const float*)d_in[12];
  const float* e_emb2 = (const float*)d_in[13];
  const float* gin_w1 = (const float*)d_in[14];
  const float* gin_b1 = (const float*)d_in[15];
  const float* gin_w2 = (const float*)d_in[16];
  const float* gin_b2 = (const float*)d_in[17];
  const float* w110 = (const float*)d_in[18];
  const float* b110 = (const float*)d_in[19];
  const float* w021 = (const float*)d_in[20];
  const float* b021 = (const float*)d_in[21];
  const float* w030 = (const float*)d_in[22];
  const float* b030 = (const float*)d_in[23];
  const float* bn_gamma = (const float*)d_in[24];
  const float* bn_beta = (const float*)d_in[25];

  int n0 = in_sizes[0] / 2, n1 = in_sizes[1] / 2;
  int E = in_sizes[2] / 2;
  int nmax = n0 > n1 ? n0 : n1;

  float* h0 = (float*)d_out;
  float* h1 = h0 + (size_t)n0 * D;

  float* ws = (float*)d_ws;
  float* z1 = ws;                       // n1*D
  float* a021 = z1 + (size_t)n1 * D;    // n1*D
  float* a110 = a021 + (size_t)n1 * D;  // n0*D
  float* a030 = a110 + (size_t)n0 * D;  // n0*D
  float* etbl = a030 + (size_t)n0 * D;  // 10*D
  float* stats = etbl + 10 * D;         // 4*D
  float* hidden = a110;                 // alias: n1*2D fits a110+a030

  // CSR region: 4 types x { rowptr(nmax+1), cursor(nmax), payload(E) }
  int* csr = (int*)(stats + 4 * D);
  size_t per = (size_t)(nmax + 1) + nmax + E;
  int* rp[4];
  int* cur[4];
  int* pay[4];
  const int* eis[4] = {ei101, ei021, ei110, ei030};
  const int* eas[4] = {ea101, ea021, ea110, ea030};
  int ndst[4] = {n1, n1, n0, n0};
  for (int t = 0; t < 4; ++t) {
    rp[t] = csr + t * per;
    cur[t] = rp[t] + (nmax + 1);
    pay[t] = cur[t] + nmax;
  }

  dim3 b256(256);
  int eBlocks = (E + 255) / 256;

  // one-time: combo table, embeddings, CSR build
  k_etbl<<<5, b256, 0, stream>>>(e_emb1, e_emb2, etbl);
  k_embed<<<(n0 * 32 + 255) / 256, b256, 0, stream>>>(x0, x_emb1, x_emb2, h0, n0);
  k_embed<<<(n1 * 32 + 255) / 256, b256, 0, stream>>>(x1, x_emb1, x_emb2, h1, n1);
  for (int t = 0; t < 4; ++t) {
    hipMemsetAsync(cur[t], 0, (size_t)ndst[t] * sizeof(int), stream);
    k_hist<<<eBlocks, b256, 0, stream>>>(eis[t], cur[t], E);
    k_scan<<<1, dim3(1024), 0, stream>>>(cur[t], rp[t], ndst[t], E);
    k_fill<<<eBlocks, b256, 0, stream>>>(eis[t], eas[t], cur[t], pay[t], E);
  }

  int gB0 = (n0 + 7) / 8, gB1 = (n1 + 7) / 8;

  for (int layer = 0; layer < 3; ++layer) {
    // aggregations (self-loop + GIN-init folded into the accumulator init)
    k_gather<2><<<gB1, b256, 0, stream>>>(h1, h1, rp[0], pay[0], etbl, z1, n1);
    k_gather<0><<<gB1, b256, 0, stream>>>(h0, nullptr, rp[1], pay[1], etbl, a021, n1);
    k_gather<0><<<gB0, b256, 0, stream>>>(h1, nullptr, rp[2], pay[2], etbl, a110, n0);
    k_gather<1><<<gB0, b256, 0, stream>>>(h0, h0, rp[3], pay[3], etbl, a030, n0);

    // out0 = 0.05*(a110@w110 + a030@w030 + b110 + b030) -> h0
    gemm_fused<128, false, true><<<(n0 + 127) / 128, b256, 0, stream>>>(
        a110, 128, w110, a030, 128, w030, b110, b030, 0.05f, 0.05f, h0, n0);
    // hidden = relu(z1 @ gin_w1 + gin_b1)  (overwrites a110/a030 region)
    gemm_fused<256, true, false><<<(n1 + 63) / 64, b256, 0, stream>>>(
        z1, 128, gin_w1, nullptr, 0, nullptr, gin_b1, nullptr, 1.0f, 0.0f,
        hidden, n1);
    // out1 = 0.5*(hidden@gin_w2 + gin_b2) + 0.05*(a021@w021 + b021) -> h1
    gemm_fused<128, false, true><<<(n1 + 127) / 128, b256, 0, stream>>>(
        hidden, 256, gin_w2, a021, 128, w021, gin_b2, b021, 0.5f, 0.05f, h1, n1);

    hipMemsetAsync(stats, 0, 4 * D * sizeof(float), stream);
    k_colsum<<<(n0 + 511) / 512, dim3(128), 0, stream>>>(h0, n0, stats);
    k_colsum<<<(n1 + 511) / 512, dim3(128), 0, stream>>>(h1, n1, stats + 2 * D);

    const float* g = bn_gamma + layer * D;
    const float* bb = bn_beta + layer * D;
    if (layer < 2) {
      k_bn<true><<<(n0 * 32 + 255) / 256, b256, 0, stream>>>(h0, n0, stats, g, bb, 1.0f / n0);
      k_bn<true><<<(n1 * 32 + 255) / 256, b256, 0, stream>>>(h1, n1, stats + 2 * D, g, bb, 1.0f / n1);
    } else {
      k_bn<false><<<(n0 * 32 + 255) / 256, b256, 0, stream>>>(h0, n0, stats, g, bb, 1.0f / n0);
      k_bn<false><<<(n1 * 32 + 255) / 256, b256, 0, stream>>>(h1, n1, stats + 2 * D, g, bb, 1.0f / n1);
    }
  }
}

// Round 3
// 1645.288 us; speedup vs baseline: 4.5880x; 1.4372x over previous
//
#include <hip/hip_runtime.h>

#define D 128
#define BN_EPS 1e-5f

// ---------------------------------------------------------------------------
// edge-attr combo table: 9 combos (a0 in 0..2, a1 in 0..2) + self-loop (4,0)
__global__ __launch_bounds__(256) void k_etbl(const float* __restrict__ e1,
                                              const float* __restrict__ e2,
                                              float* __restrict__ etbl) {
  int idx = blockIdx.x * 256 + threadIdx.x;
  if (idx < 9 * D) {
    int combo = idx / D, c = idx % D;
    int a0 = combo / 3, a1 = combo % 3;
    etbl[idx] = e1[a0 * D + c] + e2[a1 * D + c];
  } else if (idx < 10 * D) {
    int c = idx - 9 * D;
    etbl[idx] = e1[4 * D + c] + e2[c];
  }
}

// node embedding: h = x_emb1[x[:,0]] + x_emb2[x[:,1]]
__global__ __launch_bounds__(256) void k_embed(const int* __restrict__ x,
                                               const float* __restrict__ emb1,
                                               const float* __restrict__ emb2,
                                               float* __restrict__ out, int n) {
  int idx = blockIdx.x * 256 + threadIdx.x;
  if (idx >= n * (D / 4)) return;
  int node = idx >> 5, c4 = idx & 31;
  int i1 = x[2 * node], i2 = x[2 * node + 1];
  float4 v1 = *(const float4*)(emb1 + (size_t)i1 * D + c4 * 4);
  float4 v2 = *(const float4*)(emb2 + (size_t)i2 * D + c4 * 4);
  float4 o;
  o.x = v1.x + v2.x; o.y = v1.y + v2.y; o.z = v1.z + v2.z; o.w = v1.w + v2.w;
  *(float4*)(out + (size_t)node * D + c4 * 4) = o;
}

// ---------------------------------------------------------------------------
// CSR build: histogram -> single-block scan -> fill
__global__ __launch_bounds__(256) void k_hist(const int* __restrict__ ei,
                                              int* __restrict__ cursor, int E) {
  int e = blockIdx.x * 256 + threadIdx.x;
  if (e >= E) return;
  atomicAdd(&cursor[ei[E + e]], 1);
}

__global__ __launch_bounds__(1024) void k_scan(int* __restrict__ cursor,
                                               int* __restrict__ rowptr, int n,
                                               int E) {
  __shared__ int lds[1024];
  int tid = threadIdx.x;
  int chunk = (n + 1023) >> 10;
  int b = tid * chunk;
  int e = min(b + chunk, n);
  int s = 0;
  for (int i = b; i < e; ++i) s += cursor[i];
  lds[tid] = s;
  __syncthreads();
  for (int off = 1; off < 1024; off <<= 1) {
    int v = (tid >= off) ? lds[tid - off] : 0;
    __syncthreads();
    lds[tid] += v;
    __syncthreads();
  }
  int run = (tid == 0) ? 0 : lds[tid - 1];
  for (int i = b; i < e; ++i) {
    int d = cursor[i];
    rowptr[i] = run;
    cursor[i] = run;  // cursor becomes the fill position
    run += d;
  }
  if (tid == 1023) rowptr[n] = E;
}

// payload = src | (combo << 16)   (src < 65536, combo < 9)
__global__ __launch_bounds__(256) void k_fill(const int* __restrict__ ei,
                                              const int* __restrict__ ea,
                                              int* __restrict__ cursor,
                                              int* __restrict__ payload, int E) {
  int e = blockIdx.x * 256 + threadIdx.x;
  if (e >= E) return;
  int dst = ei[E + e];
  int src = ei[e];
  int combo = ea[2 * e] * 3 + ea[2 * e + 1];
  int pos = atomicAdd(&cursor[dst], 1);
  payload[pos] = src | (combo << 16);
}

// ---------------------------------------------------------------------------
// CSR gather: agg[g] = init(g) + sum_{e in edges(g)} (hsrc[src_e] + etbl[combo_e])
// MODE 0: init = 0;  MODE 1: init = hinit[g] + es;  MODE 2: init = 2.1*hinit[g] + es
template <int MODE>
__global__ __launch_bounds__(256) void k_gather(
    const float* __restrict__ hsrc, const float* __restrict__ hinit,
    const int* __restrict__ rowptr, const int* __restrict__ payload,
    const float* __restrict__ etbl, float* __restrict__ agg, int n) {
  __shared__ float et[10 * D];
  for (int i = threadIdx.x; i < 10 * D; i += 256) et[i] = etbl[i];
  __syncthreads();
  int g = blockIdx.x * 8 + (threadIdx.x >> 5);
  if (g >= n) return;
  int c = (threadIdx.x & 31) * 4;
  float4 acc;
  if (MODE == 0) {
    acc = make_float4(0.f, 0.f, 0.f, 0.f);
  } else {
    float4 h = *(const float4*)(hinit + (size_t)g * D + c);
    float4 es = *(const float4*)(et + 9 * D + c);
    float sc = (MODE == 2) ? 2.1f : 1.0f;
    acc.x = sc * h.x + es.x; acc.y = sc * h.y + es.y;
    acc.z = sc * h.z + es.z; acc.w = sc * h.w + es.w;
  }
  int e0 = rowptr[g], e1 = rowptr[g + 1];
  for (int e = e0; e < e1; ++e) {
    int p = payload[e];
    int src = p & 0xFFFF;
    int combo = p >> 16;
    float4 h = *(const float4*)(hsrc + (size_t)src * D + c);
    float4 ev = *(const float4*)(et + combo * D + c);
    acc.x += h.x + ev.x; acc.y += h.y + ev.y;
    acc.z += h.z + ev.z; acc.w += h.w + ev.w;
  }
  *(float4*)(agg + (size_t)g * D + c) = acc;
}

// ---------------------------------------------------------------------------
// fused fp32 GEMM: C = s1*(A1@W1) + s2*(A2@W2) + s1*bias1 + s2*bias2, opt ReLU
// STATS: additionally atomically accumulate per-column sum/sum^2 of C into
// stats[0..D) / stats[D..2D)  (caller must zero stats first).
template <int NCOLS, bool RELU, bool TWO, bool STATS>
__global__ __launch_bounds__(256) void gemm_fused(
    const float* __restrict__ A1, int K1, const float* __restrict__ W1,
    const float* __restrict__ A2, int K2, const float* __restrict__ W2,
    const float* __restrict__ bias1, const float* __restrict__ bias2,
    float s1, float s2, float* __restrict__ C, int M,
    float* __restrict__ stats) {
  constexpr int CG = NCOLS / 8;
  constexpr int BM = 2048 / CG;
  constexpr int BMP = BM + 4;
  __shared__ float As[32 * BMP];
  __shared__ float Ws[32 * NCOLS];

  int tid = threadIdx.x;
  int tx = tid % CG;
  int ty = tid / CG;
  int row0 = blockIdx.x * BM;

  float acc[8][8];
#pragma unroll
  for (int r = 0; r < 8; ++r)
#pragma unroll
    for (int c = 0; c < 8; ++c) acc[r][c] = 0.f;

  float rel = TWO ? (s2 / s1) : 0.f;

  for (int srci = 0; srci < (TWO ? 2 : 1); ++srci) {
    const float* A = srci ? A2 : A1;
    const float* W = srci ? W2 : W1;
    int K = srci ? K2 : K1;
    float ls = srci ? rel : 1.0f;
    for (int k0 = 0; k0 < K; k0 += 32) {
      __syncthreads();
      constexpr int AF4 = BM / 32;
#pragma unroll
      for (int p = 0; p < AF4; ++p) {
        int f = p * 256 + tid;
        int r = f >> 3;
        int c4 = f & 7;
        float4 v = make_float4(0.f, 0.f, 0.f, 0.f);
        int gr = row0 + r;
        if (gr < M) v = *(const float4*)(A + (size_t)gr * K + k0 + c4 * 4);
        int kk = c4 * 4;
        As[(kk + 0) * BMP + r] = v.x * ls;
        As[(kk + 1) * BMP + r] = v.y * ls;
        As[(kk + 2) * BMP + r] = v.z * ls;
        As[(kk + 3) * BMP + r] = v.w * ls;
      }
      constexpr int WF4 = NCOLS / 32;
#pragma unroll
      for (int p = 0; p < WF4; ++p) {
        int f = p * 256 + tid;
        int r = f / (NCOLS / 4);
        int c4 = f % (NCOLS / 4);
        *(float4*)(Ws + r * NCOLS + c4 * 4) =
            *(const float4*)(W + (size_t)(k0 + r) * NCOLS + c4 * 4);
      }
      __syncthreads();
#pragma unroll
      for (int kk = 0; kk < 32; ++kk) {
        float a[8], w[8];
        *(float4*)(a) = *(float4*)(As + kk * BMP + ty * 8);
        *(float4*)(a + 4) = *(float4*)(As + kk * BMP + ty * 8 + 4);
        *(float4*)(w) = *(float4*)(Ws + kk * NCOLS + tx * 8);
        *(float4*)(w + 4) = *(float4*)(Ws + kk * NCOLS + tx * 8 + 4);
#pragma unroll
        for (int r = 0; r < 8; ++r)
#pragma unroll
          for (int c = 0; c < 8; ++c) acc[r][c] += a[r] * w[c];
      }
    }
  }

  int colb = tx * 8;
  float bv[8];
#pragma unroll
  for (int c = 0; c < 8; ++c) {
    float b = bias1[colb + c] * s1;
    if (TWO) b += bias2[colb + c] * s2;
    bv[c] = b;
  }
  float cs[8], cq[8];
#pragma unroll
  for (int c = 0; c < 8; ++c) { cs[c] = 0.f; cq[c] = 0.f; }
#pragma unroll
  for (int r = 0; r < 8; ++r) {
    int gr = row0 + ty * 8 + r;
    if (gr >= M) continue;
    float ov[8];
#pragma unroll
    for (int c = 0; c < 8; ++c) {
      float v = acc[r][c] * s1 + bv[c];
      if (RELU) v = fmaxf(v, 0.f);
      ov[c] = v;
      if (STATS) { cs[c] += v; cq[c] += v * v; }
    }
    *(float4*)(C + (size_t)gr * NCOLS + colb) = *(float4*)(ov);
    *(float4*)(C + (size_t)gr * NCOLS + colb + 4) = *(float4*)(ov + 4);
  }

  if (STATS) {
    // reduce 16 row-groups x 128 cols through LDS (reuse As: needs 16 KB)
    __syncthreads();
    float* red = As;  // red[ty*128 + col] = sum; red[2048 + ...] = sumsq
#pragma unroll
    for (int c = 0; c < 8; ++c) {
      red[ty * 128 + colb + c] = cs[c];
      red[2048 + ty * 128 + colb + c] = cq[c];
    }
    __syncthreads();
    if (tid < 128) {
      float s = 0.f, q = 0.f;
#pragma unroll
      for (int j = 0; j < 16; ++j) {
        s += red[j * 128 + tid];
        q += red[2048 + j * 128 + tid];
      }
      atomicAdd(&stats[tid], s);
      atomicAdd(&stats[D + tid], q);
    }
  }
}

// ---------------------------------------------------------------------------
template <bool RELU>
__global__ __launch_bounds__(256) void k_bn(float* __restrict__ X, int M,
                                            const float* __restrict__ st,
                                            const float* __restrict__ gamma,
                                            const float* __restrict__ beta,
                                            float invM) {
  int idx = blockIdx.x * 256 + threadIdx.x;
  int i = idx >> 5, c4 = idx & 31;
  if (i >= M) return;
  float4 v = *(float4*)(X + (size_t)i * D + c4 * 4);
  float vv[4] = {v.x, v.y, v.z, v.w};
  float o[4];
#pragma unroll
  for (int j = 0; j < 4; ++j) {
    int d = c4 * 4 + j;
    float mu = st[d] * invM;
    float var = st[D + d] * invM - mu * mu;
    float sc = rsqrtf(var + BN_EPS) * gamma[d];
    float sh = beta[d] - mu * sc;
    float x = vv[j] * sc + sh;
    if (RELU) x = fmaxf(x, 0.f);
    o[j] = x;
  }
  *(float4*)(X + (size_t)i * D + c4 * 4) = *(float4*)o;
}

// ---------------------------------------------------------------------------
extern "C" void kernel_launch(void* const* d_in, const int* in_sizes, int n_in,
                              void* d_out, int out_size, void* d_ws,
                              size_t ws_size, hipStream_t stream) {
  const int* x0 = (const int*)d_in[0];
  const int* x1 = (const int*)d_in[1];
  const int* ei101 = (const int*)d_in[2];
  const int* ea101 = (const int*)d_in[3];
  const int* ei110 = (const int*)d_in[4];
  const int* ea110 = (const int*)d_in[5];
  const int* ei021 = (const int*)d_in[6];
  const int* ea021 = (const int*)d_in[7];
  const int* ei030 = (const int*)d_in[8];
  const int* ea030 = (const int*)d_in[9];
  const float* x_emb1 = (const float*)d_in[10];
  const float* x_emb2 = (const float*)d_in[11];
  const float* e_emb1 = (const float*)d_in[12];
  const float* e_emb2 = (const float*)d_in[13];
  const float* gin_w1 = (const float*)d_in[14];
  const float* gin_b1 = (const float*)d_in[15];
  const float* gin_w2 = (const float*)d_in[16];
  const float* gin_b2 = (const float*)d_in[17];
  const float* w110 = (const float*)d_in[18];
  const float* b110 = (const float*)d_in[19];
  const float* w021 = (const float*)d_in[20];
  const float* b021 = (const float*)d_in[21];
  const float* w030 = (const float*)d_in[22];
  const float* b030 = (const float*)d_in[23];
  const float* bn_gamma = (const float*)d_in[24];
  const float* bn_beta = (const float*)d_in[25];

  int n0 = in_sizes[0] / 2, n1 = in_sizes[1] / 2;
  int E = in_sizes[2] / 2;
  int nmax = n0 > n1 ? n0 : n1;

  float* h0 = (float*)d_out;
  float* h1 = h0 + (size_t)n0 * D;

  float* ws = (float*)d_ws;
  float* z1 = ws;                       // n1*D
  float* a021 = z1 + (size_t)n1 * D;    // n1*D
  float* a110 = a021 + (size_t)n1 * D;  // n0*D
  float* a030 = a110 + (size_t)n0 * D;  // n0*D
  float* etbl = a030 + (size_t)n0 * D;  // 10*D
  float* stats = etbl + 10 * D;         // 4*D
  float* hidden = a110;                 // alias: n1*2D fits a110+a030

  // CSR region: 4 types x { rowptr(nmax+1), cursor(nmax), payload(E) }
  int* csr = (int*)(stats + 4 * D);
  size_t per = (size_t)(nmax + 1) + nmax + E;
  int* rp[4];
  int* cur[4];
  int* pay[4];
  const int* eis[4] = {ei101, ei021, ei110, ei030};
  const int* eas[4] = {ea101, ea021, ea110, ea030};
  int ndst[4] = {n1, n1, n0, n0};
  for (int t = 0; t < 4; ++t) {
    rp[t] = csr + t * per;
    cur[t] = rp[t] + (nmax + 1);
    pay[t] = cur[t] + nmax;
  }

  dim3 b256(256);
  int eBlocks = (E + 255) / 256;

  // one-time: combo table, embeddings, CSR build
  k_etbl<<<5, b256, 0, stream>>>(e_emb1, e_emb2, etbl);
  k_embed<<<(n0 * 32 + 255) / 256, b256, 0, stream>>>(x0, x_emb1, x_emb2, h0, n0);
  k_embed<<<(n1 * 32 + 255) / 256, b256, 0, stream>>>(x1, x_emb1, x_emb2, h1, n1);
  for (int t = 0; t < 4; ++t) {
    hipMemsetAsync(cur[t], 0, (size_t)ndst[t] * sizeof(int), stream);
    k_hist<<<eBlocks, b256, 0, stream>>>(eis[t], cur[t], E);
    k_scan<<<1, dim3(1024), 0, stream>>>(cur[t], rp[t], ndst[t], E);
    k_fill<<<eBlocks, b256, 0, stream>>>(eis[t], eas[t], cur[t], pay[t], E);
  }

  int gB0 = (n0 + 7) / 8, gB1 = (n1 + 7) / 8;

  for (int layer = 0; layer < 3; ++layer) {
    // aggregations (self-loop + GIN-init folded into the accumulator init)
    k_gather<2><<<gB1, b256, 0, stream>>>(h1, h1, rp[0], pay[0], etbl, z1, n1);
    k_gather<0><<<gB1, b256, 0, stream>>>(h0, nullptr, rp[1], pay[1], etbl, a021, n1);
    k_gather<0><<<gB0, b256, 0, stream>>>(h1, nullptr, rp[2], pay[2], etbl, a110, n0);
    k_gather<1><<<gB0, b256, 0, stream>>>(h0, h0, rp[3], pay[3], etbl, a030, n0);

    hipMemsetAsync(stats, 0, 4 * D * sizeof(float), stream);

    // out0 = 0.05*(a110@w110 + a030@w030 + b110 + b030) -> h0  (+stats0)
    gemm_fused<128, false, true, true><<<(n0 + 127) / 128, b256, 0, stream>>>(
        a110, 128, w110, a030, 128, w030, b110, b030, 0.05f, 0.05f, h0, n0,
        stats);
    // hidden = relu(z1 @ gin_w1 + gin_b1)  (overwrites a110/a030 region)
    gemm_fused<256, true, false, false><<<(n1 + 63) / 64, b256, 0, stream>>>(
        z1, 128, gin_w1, nullptr, 0, nullptr, gin_b1, nullptr, 1.0f, 0.0f,
        hidden, n1, nullptr);
    // out1 = 0.5*(hidden@gin_w2 + gin_b2) + 0.05*(a021@w021 + b021) -> h1 (+stats1)
    gemm_fused<128, false, true, true><<<(n1 + 127) / 128, b256, 0, stream>>>(
        hidden, 256, gin_w2, a021, 128, w021, gin_b2, b021, 0.5f, 0.05f, h1, n1,
        stats + 2 * D);

    const float* g = bn_gamma + layer * D;
    const float* bb = bn_beta + layer * D;
    if (layer < 2) {
      k_bn<true><<<(n0 * 32 + 255) / 256, b256, 0, stream>>>(h0, n0, stats, g, bb, 1.0f / n0);
      k_bn<true><<<(n1 * 32 + 255) / 256, b256, 0, stream>>>(h1, n1, stats + 2 * D, g, bb, 1.0f / n1);
    } else {
      k_bn<false><<<(n0 * 32 + 255) / 256, b256, 0, stream>>>(h0, n0, stats, g, bb, 1.0f / n0);
      k_bn<false><<<(n1 * 32 + 255) / 256, b256, 0, stream>>>(h1, n1, stats + 2 * D, g, bb, 1.0f / n1);
    }
  }
}

// Round 4
// 1235.190 us; speedup vs baseline: 6.1113x; 1.3320x over previous
//
#include <hip/hip_runtime.h>

#define D 128
#define BN_EPS 1e-5f
#define MAXNB 16  // max scan blocks per type (n <= 65536 = MAXNB*4096)

// ---------------------------------------------------------------------------
// edge-attr combo table: 9 combos (a0 in 0..2, a1 in 0..2) + self-loop (4,0)
__global__ __launch_bounds__(256) void k_etbl(const float* __restrict__ e1,
                                              const float* __restrict__ e2,
                                              float* __restrict__ etbl) {
  int idx = blockIdx.x * 256 + threadIdx.x;
  if (idx < 9 * D) {
    int combo = idx / D, c = idx % D;
    int a0 = combo / 3, a1 = combo % 3;
    etbl[idx] = e1[a0 * D + c] + e2[a1 * D + c];
  } else if (idx < 10 * D) {
    int c = idx - 9 * D;
    etbl[idx] = e1[4 * D + c] + e2[c];
  }
}

// node embedding: h = x_emb1[x[:,0]] + x_emb2[x[:,1]]
__global__ __launch_bounds__(256) void k_embed(const int* __restrict__ x,
                                               const float* __restrict__ emb1,
                                               const float* __restrict__ emb2,
                                               float* __restrict__ out, int n) {
  int idx = blockIdx.x * 256 + threadIdx.x;
  if (idx >= n * (D / 4)) return;
  int node = idx >> 5, c4 = idx & 31;
  int i1 = x[2 * node], i2 = x[2 * node + 1];
  float4 v1 = *(const float4*)(emb1 + (size_t)i1 * D + c4 * 4);
  float4 v2 = *(const float4*)(emb2 + (size_t)i2 * D + c4 * 4);
  float4 o;
  o.x = v1.x + v2.x; o.y = v1.y + v2.y; o.z = v1.z + v2.z; o.w = v1.w + v2.w;
  *(float4*)(out + (size_t)node * D + c4 * 4) = o;
}

// ---------------------------------------------------------------------------
// CSR build: histogram -> hierarchical scan (3 dispatches, all 4 types) -> fill
__global__ __launch_bounds__(256) void k_hist(const int* __restrict__ ei,
                                              int* __restrict__ cursor, int E) {
  int e = blockIdx.x * 256 + threadIdx.x;
  if (e >= E) return;
  atomicAdd(&cursor[ei[E + e]], 1);
}

struct CsrPtrs {
  int* cur[4];
  int* rp[4];
  int n[4];
};

// per-block reduce of 4096 counts -> bsum[type*MAXNB + block]
__global__ __launch_bounds__(256) void k_scan1(CsrPtrs p, int* __restrict__ bsum) {
  __shared__ int lds[256];
  int type = blockIdx.y;
  const int* cur = p.cur[type];
  int n = p.n[type];
  int base = blockIdx.x * 4096;
  int s = 0;
  for (int i = threadIdx.x; i < 4096; i += 256) {
    int idx = base + i;
    if (idx < n) s += cur[idx];
  }
  int tid = threadIdx.x;
  lds[tid] = s;
  __syncthreads();
  for (int off = 128; off > 0; off >>= 1) {
    if (tid < off) lds[tid] += lds[tid + off];
    __syncthreads();
  }
  if (tid == 0) bsum[type * MAXNB + blockIdx.x] = lds[0];
}

// exclusive scan of block sums per type (<= MAXNB values each)
__global__ __launch_bounds__(64) void k_scan2(int* __restrict__ bsum) {
  int t = threadIdx.x;
  if (t < 4) {
    int run = 0;
    for (int i = 0; i < MAXNB; ++i) {
      int v = bsum[t * MAXNB + i];
      bsum[t * MAXNB + i] = run;
      run += v;
    }
  }
}

// per-block exclusive scan: rowptr/cursor = bsum[block] + local exclusive scan
__global__ __launch_bounds__(256) void k_scan3(CsrPtrs p,
                                               const int* __restrict__ bsum,
                                               int E) {
  __shared__ int lds[256];
  int type = blockIdx.y;
  int* cur = p.cur[type];
  int* rp = p.rp[type];
  int n = p.n[type];
  int tid = threadIdx.x;
  if (blockIdx.x == 0 && tid == 0) rp[n] = E;
  int t0 = blockIdx.x * 4096 + tid * 16;
  int loc[16];
  int s = 0;
#pragma unroll
  for (int j = 0; j < 16; ++j) {
    int idx = t0 + j;
    int v = (idx < n) ? cur[idx] : 0;
    loc[j] = s;
    s += v;
  }
  lds[tid] = s;
  __syncthreads();
  for (int off = 1; off < 256; off <<= 1) {
    int v = (tid >= off) ? lds[tid - off] : 0;
    __syncthreads();
    lds[tid] += v;
    __syncthreads();
  }
  int off0 = bsum[type * MAXNB + blockIdx.x] + ((tid == 0) ? 0 : lds[tid - 1]);
#pragma unroll
  for (int j = 0; j < 16; ++j) {
    int idx = t0 + j;
    if (idx < n) {
      int v = off0 + loc[j];
      rp[idx] = v;
      cur[idx] = v;  // cursor becomes the fill position
    }
  }
}

// payload = src | (combo << 16)   (src < 65536, combo < 9)
__global__ __launch_bounds__(256) void k_fill(const int* __restrict__ ei,
                                              const int* __restrict__ ea,
                                              int* __restrict__ cursor,
                                              int* __restrict__ payload, int E) {
  int e = blockIdx.x * 256 + threadIdx.x;
  if (e >= E) return;
  int dst = ei[E + e];
  int src = ei[e];
  int combo = ea[2 * e] * 3 + ea[2 * e + 1];
  int pos = atomicAdd(&cursor[dst], 1);
  payload[pos] = src | (combo << 16);
}

// ---------------------------------------------------------------------------
// CSR gather: agg[g] = init(g) + sum_{e in edges(g)} (hsrc[src_e] + etbl[combo_e])
// MODE 0: init = 0;  MODE 1: init = hinit[g] + es;  MODE 2: init = 2.1*hinit[g] + es
template <int MODE>
__global__ __launch_bounds__(256) void k_gather(
    const float* __restrict__ hsrc, const float* __restrict__ hinit,
    const int* __restrict__ rowptr, const int* __restrict__ payload,
    const float* __restrict__ etbl, float* __restrict__ agg, int n) {
  __shared__ float et[10 * D];
  for (int i = threadIdx.x; i < 10 * D; i += 256) et[i] = etbl[i];
  __syncthreads();
  int g = blockIdx.x * 8 + (threadIdx.x >> 5);
  if (g >= n) return;
  int c = (threadIdx.x & 31) * 4;
  float4 acc;
  if (MODE == 0) {
    acc = make_float4(0.f, 0.f, 0.f, 0.f);
  } else {
    float4 h = *(const float4*)(hinit + (size_t)g * D + c);
    float4 es = *(const float4*)(et + 9 * D + c);
    float sc = (MODE == 2) ? 2.1f : 1.0f;
    acc.x = sc * h.x + es.x; acc.y = sc * h.y + es.y;
    acc.z = sc * h.z + es.z; acc.w = sc * h.w + es.w;
  }
  int e0 = rowptr[g], e1 = rowptr[g + 1];
  for (int e = e0; e < e1; ++e) {
    int p = payload[e];
    int src = p & 0xFFFF;
    int combo = p >> 16;
    float4 h = *(const float4*)(hsrc + (size_t)src * D + c);
    float4 ev = *(const float4*)(et + combo * D + c);
    acc.x += h.x + ev.x; acc.y += h.y + ev.y;
    acc.z += h.z + ev.z; acc.w += h.w + ev.w;
  }
  *(float4*)(agg + (size_t)g * D + c) = acc;
}

// ---------------------------------------------------------------------------
// fused fp32 GEMM: C = s1*(A1@W1) + s2*(A2@W2) + s1*bias1 + s2*bias2, opt ReLU
// STATS: additionally atomically accumulate per-column sum/sum^2 of C.
template <int NCOLS, bool RELU, bool TWO, bool STATS>
__global__ __launch_bounds__(256) void gemm_fused(
    const float* __restrict__ A1, int K1, const float* __restrict__ W1,
    const float* __restrict__ A2, int K2, const float* __restrict__ W2,
    const float* __restrict__ bias1, const float* __restrict__ bias2,
    float s1, float s2, float* __restrict__ C, int M,
    float* __restrict__ stats) {
  constexpr int CG = NCOLS / 8;
  constexpr int BM = 2048 / CG;
  constexpr int BMP = BM + 4;
  __shared__ float As[32 * BMP];
  __shared__ float Ws[32 * NCOLS];

  int tid = threadIdx.x;
  int tx = tid % CG;
  int ty = tid / CG;
  int row0 = blockIdx.x * BM;

  float acc[8][8];
#pragma unroll
  for (int r = 0; r < 8; ++r)
#pragma unroll
    for (int c = 0; c < 8; ++c) acc[r][c] = 0.f;

  float rel = TWO ? (s2 / s1) : 0.f;

  for (int srci = 0; srci < (TWO ? 2 : 1); ++srci) {
    const float* A = srci ? A2 : A1;
    const float* W = srci ? W2 : W1;
    int K = srci ? K2 : K1;
    float ls = srci ? rel : 1.0f;
    for (int k0 = 0; k0 < K; k0 += 32) {
      __syncthreads();
      constexpr int AF4 = BM / 32;
#pragma unroll
      for (int p = 0; p < AF4; ++p) {
        int f = p * 256 + tid;
        int r = f >> 3;
        int c4 = f & 7;
        float4 v = make_float4(0.f, 0.f, 0.f, 0.f);
        int gr = row0 + r;
        if (gr < M) v = *(const float4*)(A + (size_t)gr * K + k0 + c4 * 4);
        int kk = c4 * 4;
        As[(kk + 0) * BMP + r] = v.x * ls;
        As[(kk + 1) * BMP + r] = v.y * ls;
        As[(kk + 2) * BMP + r] = v.z * ls;
        As[(kk + 3) * BMP + r] = v.w * ls;
      }
      constexpr int WF4 = NCOLS / 32;
#pragma unroll
      for (int p = 0; p < WF4; ++p) {
        int f = p * 256 + tid;
        int r = f / (NCOLS / 4);
        int c4 = f % (NCOLS / 4);
        *(float4*)(Ws + r * NCOLS + c4 * 4) =
            *(const float4*)(W + (size_t)(k0 + r) * NCOLS + c4 * 4);
      }
      __syncthreads();
#pragma unroll
      for (int kk = 0; kk < 32; ++kk) {
        float a[8], w[8];
        *(float4*)(a) = *(float4*)(As + kk * BMP + ty * 8);
        *(float4*)(a + 4) = *(float4*)(As + kk * BMP + ty * 8 + 4);
        *(float4*)(w) = *(float4*)(Ws + kk * NCOLS + tx * 8);
        *(float4*)(w + 4) = *(float4*)(Ws + kk * NCOLS + tx * 8 + 4);
#pragma unroll
        for (int r = 0; r < 8; ++r)
#pragma unroll
          for (int c = 0; c < 8; ++c) acc[r][c] += a[r] * w[c];
      }
    }
  }

  int colb = tx * 8;
  float bv[8];
#pragma unroll
  for (int c = 0; c < 8; ++c) {
    float b = bias1[colb + c] * s1;
    if (TWO) b += bias2[colb + c] * s2;
    bv[c] = b;
  }
  float cs[8], cq[8];
#pragma unroll
  for (int c = 0; c < 8; ++c) { cs[c] = 0.f; cq[c] = 0.f; }
#pragma unroll
  for (int r = 0; r < 8; ++r) {
    int gr = row0 + ty * 8 + r;
    if (gr >= M) continue;
    float ov[8];
#pragma unroll
    for (int c = 0; c < 8; ++c) {
      float v = acc[r][c] * s1 + bv[c];
      if (RELU) v = fmaxf(v, 0.f);
      ov[c] = v;
      if (STATS) { cs[c] += v; cq[c] += v * v; }
    }
    *(float4*)(C + (size_t)gr * NCOLS + colb) = *(float4*)(ov);
    *(float4*)(C + (size_t)gr * NCOLS + colb + 4) = *(float4*)(ov + 4);
  }

  if (STATS) {
    __syncthreads();
    float* red = As;  // reuse As (16 KB needed)
#pragma unroll
    for (int c = 0; c < 8; ++c) {
      red[ty * 128 + colb + c] = cs[c];
      red[2048 + ty * 128 + colb + c] = cq[c];
    }
    __syncthreads();
    if (tid < 128) {
      float s = 0.f, q = 0.f;
#pragma unroll
      for (int j = 0; j < 16; ++j) {
        s += red[j * 128 + tid];
        q += red[2048 + j * 128 + tid];
      }
      atomicAdd(&stats[tid], s);
      atomicAdd(&stats[D + tid], q);
    }
  }
}

// ---------------------------------------------------------------------------
template <bool RELU>
__global__ __launch_bounds__(256) void k_bn(float* __restrict__ X, int M,
                                            const float* __restrict__ st,
                                            const float* __restrict__ gamma,
                                            const float* __restrict__ beta,
                                            float invM) {
  int idx = blockIdx.x * 256 + threadIdx.x;
  int i = idx >> 5, c4 = idx & 31;
  if (i >= M) return;
  float4 v = *(float4*)(X + (size_t)i * D + c4 * 4);
  float vv[4] = {v.x, v.y, v.z, v.w};
  float o[4];
#pragma unroll
  for (int j = 0; j < 4; ++j) {
    int d = c4 * 4 + j;
    float mu = st[d] * invM;
    float var = st[D + d] * invM - mu * mu;
    float sc = rsqrtf(var + BN_EPS) * gamma[d];
    float sh = beta[d] - mu * sc;
    float x = vv[j] * sc + sh;
    if (RELU) x = fmaxf(x, 0.f);
    o[j] = x;
  }
  *(float4*)(X + (size_t)i * D + c4 * 4) = *(float4*)o;
}

// ---------------------------------------------------------------------------
extern "C" void kernel_launch(void* const* d_in, const int* in_sizes, int n_in,
                              void* d_out, int out_size, void* d_ws,
                              size_t ws_size, hipStream_t stream) {
  const int* x0 = (const int*)d_in[0];
  const int* x1 = (const int*)d_in[1];
  const int* ei101 = (const int*)d_in[2];
  const int* ea101 = (const int*)d_in[3];
  const int* ei110 = (const int*)d_in[4];
  const int* ea110 = (const int*)d_in[5];
  const int* ei021 = (const int*)d_in[6];
  const int* ea021 = (const int*)d_in[7];
  const int* ei030 = (const int*)d_in[8];
  const int* ea030 = (const int*)d_in[9];
  const float* x_emb1 = (const float*)d_in[10];
  const float* x_emb2 = (const float*)d_in[11];
  const float* e_emb1 = (const float*)d_in[12];
  const float* e_emb2 = (const float*)d_in[13];
  const float* gin_w1 = (const float*)d_in[14];
  const float* gin_b1 = (const float*)d_in[15];
  const float* gin_w2 = (const float*)d_in[16];
  const float* gin_b2 = (const float*)d_in[17];
  const float* w110 = (const float*)d_in[18];
  const float* b110 = (const float*)d_in[19];
  const float* w021 = (const float*)d_in[20];
  const float* b021 = (const float*)d_in[21];
  const float* w030 = (const float*)d_in[22];
  const float* b030 = (const float*)d_in[23];
  const float* bn_gamma = (const float*)d_in[24];
  const float* bn_beta = (const float*)d_in[25];

  int n0 = in_sizes[0] / 2, n1 = in_sizes[1] / 2;
  int E = in_sizes[2] / 2;
  int nmax = n0 > n1 ? n0 : n1;

  float* h0 = (float*)d_out;
  float* h1 = h0 + (size_t)n0 * D;

  float* ws = (float*)d_ws;
  float* z1 = ws;                       // n1*D
  float* a021 = z1 + (size_t)n1 * D;    // n1*D
  float* a110 = a021 + (size_t)n1 * D;  // n0*D
  float* a030 = a110 + (size_t)n0 * D;  // n0*D
  float* etbl = a030 + (size_t)n0 * D;  // 10*D
  float* stats = etbl + 10 * D;         // 4*D
  float* hidden = a110;                 // alias: n1*2D fits a110+a030

  // CSR region: 4 types x { rowptr(nmax+1), cursor(nmax), payload(E) } + bsum
  int* csr = (int*)(stats + 4 * D);
  size_t per = (size_t)(nmax + 1) + nmax + E;
  CsrPtrs cp;
  int* pay[4];
  const int* eis[4] = {ei101, ei021, ei110, ei030};
  const int* eas[4] = {ea101, ea021, ea110, ea030};
  int ndst[4] = {n1, n1, n0, n0};
  for (int t = 0; t < 4; ++t) {
    cp.rp[t] = csr + t * per;
    cp.cur[t] = cp.rp[t] + (nmax + 1);
    pay[t] = cp.cur[t] + nmax;
    cp.n[t] = ndst[t];
  }
  int* bsum = csr + 4 * per;  // 4*MAXNB ints

  dim3 b256(256);
  int eBlocks = (E + 255) / 256;

  // one-time: combo table, embeddings, CSR build
  k_etbl<<<5, b256, 0, stream>>>(e_emb1, e_emb2, etbl);
  k_embed<<<(n0 * 32 + 255) / 256, b256, 0, stream>>>(x0, x_emb1, x_emb2, h0, n0);
  k_embed<<<(n1 * 32 + 255) / 256, b256, 0, stream>>>(x1, x_emb1, x_emb2, h1, n1);
  for (int t = 0; t < 4; ++t) {
    hipMemsetAsync(cp.cur[t], 0, (size_t)ndst[t] * sizeof(int), stream);
    k_hist<<<eBlocks, b256, 0, stream>>>(eis[t], cp.cur[t], E);
  }
  hipMemsetAsync(bsum, 0, 4 * MAXNB * sizeof(int), stream);
  int nb = (nmax + 4095) / 4096;
  k_scan1<<<dim3(nb, 4), b256, 0, stream>>>(cp, bsum);
  k_scan2<<<1, dim3(64), 0, stream>>>(bsum);
  k_scan3<<<dim3(nb, 4), b256, 0, stream>>>(cp, bsum, E);
  for (int t = 0; t < 4; ++t)
    k_fill<<<eBlocks, b256, 0, stream>>>(eis[t], eas[t], cp.cur[t], pay[t], E);

  int gB0 = (n0 + 7) / 8, gB1 = (n1 + 7) / 8;

  for (int layer = 0; layer < 3; ++layer) {
    // aggregations (self-loop + GIN-init folded into the accumulator init)
    k_gather<2><<<gB1, b256, 0, stream>>>(h1, h1, cp.rp[0], pay[0], etbl, z1, n1);
    k_gather<0><<<gB1, b256, 0, stream>>>(h0, nullptr, cp.rp[1], pay[1], etbl, a021, n1);
    k_gather<0><<<gB0, b256, 0, stream>>>(h1, nullptr, cp.rp[2], pay[2], etbl, a110, n0);
    k_gather<1><<<gB0, b256, 0, stream>>>(h0, h0, cp.rp[3], pay[3], etbl, a030, n0);

    hipMemsetAsync(stats, 0, 4 * D * sizeof(float), stream);

    // out0 = 0.05*(a110@w110 + a030@w030 + b110 + b030) -> h0  (+stats0)
    gemm_fused<128, false, true, true><<<(n0 + 127) / 128, b256, 0, stream>>>(
        a110, 128, w110, a030, 128, w030, b110, b030, 0.05f, 0.05f, h0, n0,
        stats);
    // hidden = relu(z1 @ gin_w1 + gin_b1)  (overwrites a110/a030 region)
    gemm_fused<256, true, false, false><<<(n1 + 63) / 64, b256, 0, stream>>>(
        z1, 128, gin_w1, nullptr, 0, nullptr, gin_b1, nullptr, 1.0f, 0.0f,
        hidden, n1, nullptr);
    // out1 = 0.5*(hidden@gin_w2 + gin_b2) + 0.05*(a021@w021 + b021) -> h1 (+stats1)
    gemm_fused<128, false, true, true><<<(n1 + 127) / 128, b256, 0, stream>>>(
        hidden, 256, gin_w2, a021, 128, w021, gin_b2, b021, 0.5f, 0.05f, h1, n1,
        stats + 2 * D);

    const float* g = bn_gamma + layer * D;
    const float* bb = bn_beta + layer * D;
    if (layer < 2) {
      k_bn<true><<<(n0 * 32 + 255) / 256, b256, 0, stream>>>(h0, n0, stats, g, bb, 1.0f / n0);
      k_bn<true><<<(n1 * 32 + 255) / 256, b256, 0, stream>>>(h1, n1, stats + 2 * D, g, bb, 1.0f / n1);
    } else {
      k_bn<false><<<(n0 * 32 + 255) / 256, b256, 0, stream>>>(h0, n0, stats, g, bb, 1.0f / n0);
      k_bn<false><<<(n1 * 32 + 255) / 256, b256, 0, stream>>>(h1, n1, stats + 2 * D, g, bb, 1.0f / n1);
    }
  }
}

// Round 5
// 1016.896 us; speedup vs baseline: 7.4232x; 1.2147x over previous
//
#include <hip/hip_runtime.h>

#define D 128
#define BN_EPS 1e-5f
#define MAXNB 16  // max scan blocks per type (n <= 65536 = MAXNB*4096)

typedef __attribute__((ext_vector_type(8))) short bf16x8;
typedef __attribute__((ext_vector_type(4))) float f32x4;

__device__ __forceinline__ unsigned short f2bf(float x) {
  unsigned u = __float_as_uint(x);
  u += 0x7FFF + ((u >> 16) & 1);  // round-to-nearest-even
  return (unsigned short)(u >> 16);
}

// ---------------------------------------------------------------------------
// edge-attr combo table: 9 combos (a0 in 0..2, a1 in 0..2) + self-loop (4,0)
__global__ __launch_bounds__(256) void k_etbl(const float* __restrict__ e1,
                                              const float* __restrict__ e2,
                                              float* __restrict__ etbl) {
  int idx = blockIdx.x * 256 + threadIdx.x;
  if (idx < 9 * D) {
    int combo = idx / D, c = idx % D;
    int a0 = combo / 3, a1 = combo % 3;
    etbl[idx] = e1[a0 * D + c] + e2[a1 * D + c];
  } else if (idx < 10 * D) {
    int c = idx - 9 * D;
    etbl[idx] = e1[4 * D + c] + e2[c];
  }
}

// node embedding: h = x_emb1[x[:,0]] + x_emb2[x[:,1]]
__global__ __launch_bounds__(256) void k_embed(const int* __restrict__ x,
                                               const float* __restrict__ emb1,
                                               const float* __restrict__ emb2,
                                               float* __restrict__ out, int n) {
  int idx = blockIdx.x * 256 + threadIdx.x;
  if (idx >= n * (D / 4)) return;
  int node = idx >> 5, c4 = idx & 31;
  int i1 = x[2 * node], i2 = x[2 * node + 1];
  float4 v1 = *(const float4*)(emb1 + (size_t)i1 * D + c4 * 4);
  float4 v2 = *(const float4*)(emb2 + (size_t)i2 * D + c4 * 4);
  float4 o;
  o.x = v1.x + v2.x; o.y = v1.y + v2.y; o.z = v1.z + v2.z; o.w = v1.w + v2.w;
  *(float4*)(out + (size_t)node * D + c4 * 4) = o;
}

// ---------------------------------------------------------------------------
// weight prep: Wt[n][k] = bf16(W[k][n] * scale)
__global__ __launch_bounds__(256) void k_wprep(const float* __restrict__ W,
                                               unsigned short* __restrict__ Wt,
                                               int K, int N, float scale) {
  int idx = blockIdx.x * 256 + threadIdx.x;
  if (idx >= K * N) return;
  int n = idx / K, k = idx - n * K;
  Wt[idx] = f2bf(W[(size_t)k * N + n] * scale);
}

// combined pre-scaled biases
__global__ __launch_bounds__(256) void k_bprep(
    const float* __restrict__ b110, const float* __restrict__ b030,
    const float* __restrict__ gb1, const float* __restrict__ gb2,
    const float* __restrict__ b021, float* __restrict__ bias0,
    float* __restrict__ biash, float* __restrict__ bias1) {
  int i = threadIdx.x;
  if (i < 128) {
    bias0[i] = 0.05f * (b110[i] + b030[i]);
    bias1[i] = 0.5f * gb2[i] + 0.05f * b021[i];
  }
  biash[i] = gb1[i];
}

// ---------------------------------------------------------------------------
// CSR build: histogram -> hierarchical scan (3 dispatches, all 4 types) -> fill
__global__ __launch_bounds__(256) void k_hist(const int* __restrict__ ei,
                                              int* __restrict__ cursor, int E) {
  int e = blockIdx.x * 256 + threadIdx.x;
  if (e >= E) return;
  atomicAdd(&cursor[ei[E + e]], 1);
}

struct CsrPtrs {
  int* cur[4];
  int* rp[4];
  int n[4];
};

__global__ __launch_bounds__(256) void k_scan1(CsrPtrs p, int* __restrict__ bsum) {
  __shared__ int lds[256];
  int type = blockIdx.y;
  const int* cur = p.cur[type];
  int n = p.n[type];
  int base = blockIdx.x * 4096;
  int s = 0;
  for (int i = threadIdx.x; i < 4096; i += 256) {
    int idx = base + i;
    if (idx < n) s += cur[idx];
  }
  int tid = threadIdx.x;
  lds[tid] = s;
  __syncthreads();
  for (int off = 128; off > 0; off >>= 1) {
    if (tid < off) lds[tid] += lds[tid + off];
    __syncthreads();
  }
  if (tid == 0) bsum[type * MAXNB + blockIdx.x] = lds[0];
}

__global__ __launch_bounds__(64) void k_scan2(int* __restrict__ bsum) {
  int t = threadIdx.x;
  if (t < 4) {
    int run = 0;
    for (int i = 0; i < MAXNB; ++i) {
      int v = bsum[t * MAXNB + i];
      bsum[t * MAXNB + i] = run;
      run += v;
    }
  }
}

__global__ __launch_bounds__(256) void k_scan3(CsrPtrs p,
                                               const int* __restrict__ bsum,
                                               int E) {
  __shared__ int lds[256];
  int type = blockIdx.y;
  int* cur = p.cur[type];
  int* rp = p.rp[type];
  int n = p.n[type];
  int tid = threadIdx.x;
  if (blockIdx.x == 0 && tid == 0) rp[n] = E;
  int t0 = blockIdx.x * 4096 + tid * 16;
  int loc[16];
  int s = 0;
#pragma unroll
  for (int j = 0; j < 16; ++j) {
    int idx = t0 + j;
    int v = (idx < n) ? cur[idx] : 0;
    loc[j] = s;
    s += v;
  }
  lds[tid] = s;
  __syncthreads();
  for (int off = 1; off < 256; off <<= 1) {
    int v = (tid >= off) ? lds[tid - off] : 0;
    __syncthreads();
    lds[tid] += v;
    __syncthreads();
  }
  int off0 = bsum[type * MAXNB + blockIdx.x] + ((tid == 0) ? 0 : lds[tid - 1]);
#pragma unroll
  for (int j = 0; j < 16; ++j) {
    int idx = t0 + j;
    if (idx < n) {
      int v = off0 + loc[j];
      rp[idx] = v;
      cur[idx] = v;  // cursor becomes the fill position
    }
  }
}

// payload = src | (combo << 16)   (src < 65536, combo < 9)
__global__ __launch_bounds__(256) void k_fill(const int* __restrict__ ei,
                                              const int* __restrict__ ea,
                                              int* __restrict__ cursor,
                                              int* __restrict__ payload, int E) {
  int e = blockIdx.x * 256 + threadIdx.x;
  if (e >= E) return;
  int dst = ei[E + e];
  int src = ei[e];
  int combo = ea[2 * e] * 3 + ea[2 * e + 1];
  int pos = atomicAdd(&cursor[dst], 1);
  payload[pos] = src | (combo << 16);
}

// ---------------------------------------------------------------------------
// CSR gather -> bf16 output.
// MODE 0: init = 0;  MODE 1: init = hinit[g] + es;  MODE 2: init = 2.1*hinit[g] + es
template <int MODE>
__global__ __launch_bounds__(256) void k_gather(
    const float* __restrict__ hsrc, const float* __restrict__ hinit,
    const int* __restrict__ rowptr, const int* __restrict__ payload,
    const float* __restrict__ etbl, unsigned short* __restrict__ agg, int n) {
  __shared__ float et[10 * D];
  for (int i = threadIdx.x; i < 10 * D; i += 256) et[i] = etbl[i];
  __syncthreads();
  int g = blockIdx.x * 8 + (threadIdx.x >> 5);
  if (g >= n) return;
  int c = (threadIdx.x & 31) * 4;
  float4 acc;
  if (MODE == 0) {
    acc = make_float4(0.f, 0.f, 0.f, 0.f);
  } else {
    float4 h = *(const float4*)(hinit + (size_t)g * D + c);
    float4 es = *(const float4*)(et + 9 * D + c);
    float sc = (MODE == 2) ? 2.1f : 1.0f;
    acc.x = sc * h.x + es.x; acc.y = sc * h.y + es.y;
    acc.z = sc * h.z + es.z; acc.w = sc * h.w + es.w;
  }
  int e0 = rowptr[g], e1 = rowptr[g + 1];
  for (int e = e0; e < e1; ++e) {
    int p = payload[e];
    int src = p & 0xFFFF;
    int combo = p >> 16;
    float4 h = *(const float4*)(hsrc + (size_t)src * D + c);
    float4 ev = *(const float4*)(et + combo * D + c);
    acc.x += h.x + ev.x; acc.y += h.y + ev.y;
    acc.z += h.z + ev.z; acc.w += h.w + ev.w;
  }
  ushort4 o;
  o.x = f2bf(acc.x); o.y = f2bf(acc.y); o.z = f2bf(acc.z); o.w = f2bf(acc.w);
  *(ushort4*)(agg + (size_t)g * D + c) = o;
}

// ---------------------------------------------------------------------------
// bf16 MFMA GEMM: C = A1@Wt1^T + A2@Wt2^T + bias  (scales folded into Wt/bias)
// A row-major bf16 [M][K]; Wt bf16 [N][K] (pre-transposed, pre-scaled).
// Block = 128 threads (2 waves), BM = 64 rows (32/wave). No LDS, no barriers:
// each A fragment is read once (16B/lane contiguous) and reused over all N.
// Fragment layouts (m89/m97-verified):
//   A: row = l&15, k = (l>>4)*8 + j    B: col = l&15, k = (l>>4)*8 + j
//   D: col = l&15, row = (l>>4)*4 + r
template <int KK, int NF>
__device__ __forceinline__ void kloop(const unsigned short* __restrict__ A,
                                      const unsigned short* __restrict__ Wt,
                                      int rbase, int lr, int lk,
                                      f32x4 (&acc)[2][NF]) {
#pragma unroll
  for (int k0 = 0; k0 < KK; k0 += 32) {
    bf16x8 a0 = *(const bf16x8*)(A + (size_t)(rbase + lr) * KK + k0 + lk * 8);
    bf16x8 a1 = *(const bf16x8*)(A + (size_t)(rbase + 16 + lr) * KK + k0 + lk * 8);
#pragma unroll
    for (int nf = 0; nf < NF; ++nf) {
      bf16x8 b = *(const bf16x8*)(Wt + (size_t)(nf * 16 + lr) * KK + k0 + lk * 8);
      acc[0][nf] = __builtin_amdgcn_mfma_f32_16x16x32_bf16(a0, b, acc[0][nf], 0, 0, 0);
      acc[1][nf] = __builtin_amdgcn_mfma_f32_16x16x32_bf16(a1, b, acc[1][nf], 0, 0, 0);
    }
  }
}

template <int NCOLS, int K1, int K2, bool RELU, bool STATS, bool OBF16>
__global__ __launch_bounds__(128) void gemm_mfma(
    const unsigned short* __restrict__ A1, const unsigned short* __restrict__ Wt1,
    const unsigned short* __restrict__ A2, const unsigned short* __restrict__ Wt2,
    const float* __restrict__ bias, void* __restrict__ Cv, int M,
    float* __restrict__ stats) {
  constexpr int NF = NCOLS / 16;
  __shared__ float red[STATS ? 4 * NCOLS : 1];
  int tid = threadIdx.x;
  int w = tid >> 6;
  int l = tid & 63;
  int lr = l & 15, lk = l >> 4;
  int row0 = blockIdx.x * 64 + 32 * w;

  f32x4 acc[2][NF];
#pragma unroll
  for (int mf = 0; mf < 2; ++mf)
#pragma unroll
    for (int nf = 0; nf < NF; ++nf) acc[mf][nf] = (f32x4)(0.f);

  kloop<K1, NF>(A1, Wt1, row0, lr, lk, acc);
  if constexpr (K2 > 0) kloop<K2, NF>(A2, Wt2, row0, lr, lk, acc);

  float colS[NF], colQ[NF];
#pragma unroll
  for (int nf = 0; nf < NF; ++nf) { colS[nf] = 0.f; colQ[nf] = 0.f; }

  float* Cf = (float*)Cv;
  unsigned short* Cb = (unsigned short*)Cv;
#pragma unroll
  for (int mf = 0; mf < 2; ++mf) {
#pragma unroll
    for (int r = 0; r < 4; ++r) {
      int row = row0 + 16 * mf + lk * 4 + r;
      bool ok = row < M;
#pragma unroll
      for (int nf = 0; nf < NF; ++nf) {
        int col = nf * 16 + lr;
        float v = acc[mf][nf][r] + bias[col];
        if (RELU) v = fmaxf(v, 0.f);
        if (ok) {
          if (OBF16)
            Cb[(size_t)row * NCOLS + col] = f2bf(v);
          else
            Cf[(size_t)row * NCOLS + col] = v;
          if (STATS) { colS[nf] += v; colQ[nf] += v * v; }
        }
      }
    }
  }

  if constexpr (STATS) {
#pragma unroll
    for (int nf = 0; nf < NF; ++nf) {
      float s = colS[nf], q = colQ[nf];
      s += __shfl_xor(s, 16); q += __shfl_xor(q, 16);
      s += __shfl_xor(s, 32); q += __shfl_xor(q, 32);
      if (lk == 0) {
        red[w * NCOLS + nf * 16 + lr] = s;
        red[2 * NCOLS + w * NCOLS + nf * 16 + lr] = q;
      }
    }
    __syncthreads();
    if (tid < NCOLS) {
      atomicAdd(&stats[tid], red[tid] + red[NCOLS + tid]);
      atomicAdd(&stats[D + tid], red[2 * NCOLS + tid] + red[3 * NCOLS + tid]);
    }
  }
}

// ---------------------------------------------------------------------------
template <bool RELU>
__global__ __launch_bounds__(256) void k_bn(float* __restrict__ X, int M,
                                            const float* __restrict__ st,
                                            const float* __restrict__ gamma,
                                            const float* __restrict__ beta,
                                            float invM) {
  int idx = blockIdx.x * 256 + threadIdx.x;
  int i = idx >> 5, c4 = idx & 31;
  if (i >= M) return;
  float4 v = *(float4*)(X + (size_t)i * D + c4 * 4);
  float vv[4] = {v.x, v.y, v.z, v.w};
  float o[4];
#pragma unroll
  for (int j = 0; j < 4; ++j) {
    int d = c4 * 4 + j;
    float mu = st[d] * invM;
    float var = st[D + d] * invM - mu * mu;
    float sc = rsqrtf(var + BN_EPS) * gamma[d];
    float sh = beta[d] - mu * sc;
    float x = vv[j] * sc + sh;
    if (RELU) x = fmaxf(x, 0.f);
    o[j] = x;
  }
  *(float4*)(X + (size_t)i * D + c4 * 4) = *(float4*)o;
}

// ---------------------------------------------------------------------------
extern "C" void kernel_launch(void* const* d_in, const int* in_sizes, int n_in,
                              void* d_out, int out_size, void* d_ws,
                              size_t ws_size, hipStream_t stream) {
  const int* x0 = (const int*)d_in[0];
  const int* x1 = (const int*)d_in[1];
  const int* ei101 = (const int*)d_in[2];
  const int* ea101 = (const int*)d_in[3];
  const int* ei110 = (const int*)d_in[4];
  const int* ea110 = (const int*)d_in[5];
  const int* ei021 = (const int*)d_in[6];
  const int* ea021 = (const int*)d_in[7];
  const int* ei030 = (const int*)d_in[8];
  const int* ea030 = (const int*)d_in[9];
  const float* x_emb1 = (const float*)d_in[10];
  const float* x_emb2 = (const float*)d_in[11];
  const float* e_emb1 = (const float*)d_in[12];
  const float* e_emb2 = (const float*)d_in[13];
  const float* gin_w1 = (const float*)d_in[14];
  const float* gin_b1 = (const float*)d_in[15];
  const float* gin_w2 = (const float*)d_in[16];
  const float* gin_b2 = (const float*)d_in[17];
  const float* w110 = (const float*)d_in[18];
  const float* b110 = (const float*)d_in[19];
  const float* w021 = (const float*)d_in[20];
  const float* b021 = (const float*)d_in[21];
  const float* w030 = (const float*)d_in[22];
  const float* b030 = (const float*)d_in[23];
  const float* bn_gamma = (const float*)d_in[24];
  const float* bn_beta = (const float*)d_in[25];

  int n0 = in_sizes[0] / 2, n1 = in_sizes[1] / 2;
  int E = in_sizes[2] / 2;
  int nmax = n0 > n1 ? n0 : n1;

  float* h0 = (float*)d_out;
  float* h1 = h0 + (size_t)n0 * D;

  // ---- workspace layout (byte-based, 64B aligned) ----
  char* p = (char*)d_ws;
  auto alloc = [&](size_t bytes) {
    char* r = p;
    p += (bytes + 63) & ~(size_t)63;
    return r;
  };
  unsigned short* z1b = (unsigned short*)alloc((size_t)n1 * D * 2);
  unsigned short* a021b = (unsigned short*)alloc((size_t)n1 * D * 2);
  unsigned short* a110b = (unsigned short*)alloc((size_t)n0 * D * 2);
  unsigned short* a030b = (unsigned short*)alloc((size_t)n0 * D * 2);
  unsigned short* hiddenb = (unsigned short*)alloc((size_t)n1 * 256 * 2);
  float* etbl = (float*)alloc(10 * D * 4);
  float* stats = (float*)alloc(4 * D * 4);
  unsigned short* wt110 = (unsigned short*)alloc(128 * 128 * 2);
  unsigned short* wt030 = (unsigned short*)alloc(128 * 128 * 2);
  unsigned short* wt021 = (unsigned short*)alloc(128 * 128 * 2);
  unsigned short* wtg1 = (unsigned short*)alloc(256 * 128 * 2);  // [N=256][K=128]
  unsigned short* wtg2 = (unsigned short*)alloc(128 * 256 * 2);  // [N=128][K=256]
  float* bias0 = (float*)alloc(128 * 4);
  float* biash = (float*)alloc(256 * 4);
  float* bias1 = (float*)alloc(128 * 4);

  CsrPtrs cp;
  int* pay[4];
  const int* eis[4] = {ei101, ei021, ei110, ei030};
  const int* eas[4] = {ea101, ea021, ea110, ea030};
  int ndst[4] = {n1, n1, n0, n0};
  for (int t = 0; t < 4; ++t) {
    cp.rp[t] = (int*)alloc((size_t)(nmax + 1) * 4);
    cp.cur[t] = (int*)alloc((size_t)nmax * 4);
    pay[t] = (int*)alloc((size_t)E * 4);
    cp.n[t] = ndst[t];
  }
  int* bsum = (int*)alloc(4 * MAXNB * 4);

  dim3 b256(256);
  int eBlocks = (E + 255) / 256;

  // one-time: tables, embeddings, weight prep, CSR build
  k_etbl<<<5, b256, 0, stream>>>(e_emb1, e_emb2, etbl);
  k_embed<<<(n0 * 32 + 255) / 256, b256, 0, stream>>>(x0, x_emb1, x_emb2, h0, n0);
  k_embed<<<(n1 * 32 + 255) / 256, b256, 0, stream>>>(x1, x_emb1, x_emb2, h1, n1);
  k_wprep<<<64, b256, 0, stream>>>(w110, wt110, 128, 128, 0.05f);
  k_wprep<<<64, b256, 0, stream>>>(w030, wt030, 128, 128, 0.05f);
  k_wprep<<<64, b256, 0, stream>>>(w021, wt021, 128, 128, 0.05f);
  k_wprep<<<128, b256, 0, stream>>>(gin_w1, wtg1, 128, 256, 1.0f);
  k_wprep<<<128, b256, 0, stream>>>(gin_w2, wtg2, 256, 128, 0.5f);
  k_bprep<<<1, b256, 0, stream>>>(b110, b030, gin_b1, gin_b2, b021, bias0, biash, bias1);

  for (int t = 0; t < 4; ++t) {
    hipMemsetAsync(cp.cur[t], 0, (size_t)ndst[t] * sizeof(int), stream);
    k_hist<<<eBlocks, b256, 0, stream>>>(eis[t], cp.cur[t], E);
  }
  hipMemsetAsync(bsum, 0, 4 * MAXNB * sizeof(int), stream);
  int nb = (nmax + 4095) / 4096;
  k_scan1<<<dim3(nb, 4), b256, 0, stream>>>(cp, bsum);
  k_scan2<<<1, dim3(64), 0, stream>>>(bsum);
  k_scan3<<<dim3(nb, 4), b256, 0, stream>>>(cp, bsum, E);
  for (int t = 0; t < 4; ++t)
    k_fill<<<eBlocks, b256, 0, stream>>>(eis[t], eas[t], cp.cur[t], pay[t], E);

  int gB0 = (n0 + 7) / 8, gB1 = (n1 + 7) / 8;
  int mB0 = (n0 + 63) / 64, mB1 = (n1 + 63) / 64;

  for (int layer = 0; layer < 3; ++layer) {
    // aggregations (self-loop + GIN-init folded into the accumulator init)
    k_gather<2><<<gB1, b256, 0, stream>>>(h1, h1, cp.rp[0], pay[0], etbl, z1b, n1);
    k_gather<0><<<gB1, b256, 0, stream>>>(h0, nullptr, cp.rp[1], pay[1], etbl, a021b, n1);
    k_gather<0><<<gB0, b256, 0, stream>>>(h1, nullptr, cp.rp[2], pay[2], etbl, a110b, n0);
    k_gather<1><<<gB0, b256, 0, stream>>>(h0, h0, cp.rp[3], pay[3], etbl, a030b, n0);

    hipMemsetAsync(stats, 0, 4 * D * sizeof(float), stream);

    // out0 = a110@(0.05 w110) + a030@(0.05 w030) + bias0 -> h0 (+stats0)
    gemm_mfma<128, 128, 128, false, true, false><<<mB0, 128, 0, stream>>>(
        a110b, wt110, a030b, wt030, bias0, h0, n0, stats);
    // hidden = relu(z1@gin_w1 + gin_b1) -> bf16
    gemm_mfma<256, 128, 0, true, false, true><<<mB1, 128, 0, stream>>>(
        z1b, wtg1, nullptr, nullptr, biash, hiddenb, n1, nullptr);
    // out1 = hidden@(0.5 gin_w2) + a021@(0.05 w021) + bias1 -> h1 (+stats1)
    gemm_mfma<128, 256, 128, false, true, false><<<mB1, 128, 0, stream>>>(
        hiddenb, wtg2, a021b, wt021, bias1, h1, n1, stats + 2 * D);

    const float* g = bn_gamma + layer * D;
    const float* bb = bn_beta + layer * D;
    if (layer < 2) {
      k_bn<true><<<(n0 * 32 + 255) / 256, b256, 0, stream>>>(h0, n0, stats, g, bb, 1.0f / n0);
      k_bn<true><<<(n1 * 32 + 255) / 256, b256, 0, stream>>>(h1, n1, stats + 2 * D, g, bb, 1.0f / n1);
    } else {
      k_bn<false><<<(n0 * 32 + 255) / 256, b256, 0, stream>>>(h0, n0, stats, g, bb, 1.0f / n0);
      k_bn<false><<<(n1 * 32 + 255) / 256, b256, 0, stream>>>(h1, n1, stats + 2 * D, g, bb, 1.0f / n1);
    }
  }
}

// Round 6
// 919.970 us; speedup vs baseline: 8.2052x; 1.1054x over previous
//
#include <hip/hip_runtime.h>

#define D 128
#define BN_EPS 1e-5f
#define MAXNB 16  // max scan blocks per type (n <= 65536)

typedef __attribute__((ext_vector_type(8))) short bf16x8;
typedef __attribute__((ext_vector_type(4))) float f32x4;

__device__ __forceinline__ unsigned short f2bf(float x) {
  unsigned u = __float_as_uint(x);
  u += 0x7FFF + ((u >> 16) & 1);  // round-to-nearest-even
  return (unsigned short)(u >> 16);
}
__device__ __forceinline__ float bf2f(unsigned short u) {
  return __uint_as_float((unsigned)u << 16);
}

// ---------------------------------------------------------------------------
// edge-attr combo table: 9 combos + self-loop (4,0) at slot 9
__global__ __launch_bounds__(256) void k_etbl(const float* __restrict__ e1,
                                              const float* __restrict__ e2,
                                              float* __restrict__ etbl) {
  int idx = blockIdx.x * 256 + threadIdx.x;
  if (idx < 9 * D) {
    int combo = idx / D, c = idx % D;
    etbl[idx] = e1[(combo / 3) * D + c] + e2[(combo % 3) * D + c];
  } else if (idx < 10 * D) {
    int c = idx - 9 * D;
    etbl[idx] = e1[4 * D + c] + e2[c];
  }
}

// node embedding -> bf16 h
__global__ __launch_bounds__(256) void k_embed(const int* __restrict__ x,
                                               const float* __restrict__ emb1,
                                               const float* __restrict__ emb2,
                                               unsigned short* __restrict__ out,
                                               int n) {
  int idx = blockIdx.x * 256 + threadIdx.x;
  if (idx >= n * 32) return;
  int node = idx >> 5, c4 = idx & 31;
  int i1 = x[2 * node], i2 = x[2 * node + 1];
  float4 v1 = *(const float4*)(emb1 + (size_t)i1 * D + c4 * 4);
  float4 v2 = *(const float4*)(emb2 + (size_t)i2 * D + c4 * 4);
  ushort4 o;
  o.x = f2bf(v1.x + v2.x); o.y = f2bf(v1.y + v2.y);
  o.z = f2bf(v1.z + v2.z); o.w = f2bf(v1.w + v2.w);
  *(ushort4*)(out + (size_t)node * D + c4 * 4) = o;
}

// ---------------------------------------------------------------------------
// weight prep: Wt[n][k] = bf16(W[k][n] * scale)
__global__ __launch_bounds__(256) void k_wprep(const float* __restrict__ W,
                                               unsigned short* __restrict__ Wt,
                                               int K, int N, float scale) {
  int idx = blockIdx.x * 256 + threadIdx.x;
  if (idx >= K * N) return;
  int n = idx / K, k = idx - n * K;
  Wt[idx] = f2bf(W[(size_t)k * N + n] * scale);
}

__global__ __launch_bounds__(256) void k_bprep(
    const float* __restrict__ b110, const float* __restrict__ b030,
    const float* __restrict__ gb1, const float* __restrict__ gb2,
    const float* __restrict__ b021, float* __restrict__ bias0,
    float* __restrict__ biash, float* __restrict__ bias1) {
  int i = threadIdx.x;
  if (i < 128) {
    bias0[i] = 0.05f * (b110[i] + b030[i]);
    bias1[i] = 0.5f * gb2[i] + 0.05f * b021[i];
  }
  biash[i] = gb1[i];
}

// ---------------------------------------------------------------------------
// CSR build (all 4 edge types via grid.y)
struct EdgeArr {
  const int* ei[4];
  const int* ea[4];
  int* cur[4];
  int* pay[4];
};
struct CsrPtrs {
  int* cur[4];
  int* rp[4];
  int n[4];
};

__global__ __launch_bounds__(256) void k_hist4(EdgeArr A, int E) {
  int t = blockIdx.y;
  int e = blockIdx.x * 256 + threadIdx.x;
  if (e >= E) return;
  atomicAdd(&A.cur[t][A.ei[t][E + e]], 1);
}

__global__ __launch_bounds__(256) void k_scan1(CsrPtrs p, int* __restrict__ bsum) {
  __shared__ int lds[256];
  int type = blockIdx.y;
  const int* cur = p.cur[type];
  int n = p.n[type];
  int base = blockIdx.x * 4096;
  int s = 0;
  for (int i = threadIdx.x; i < 4096; i += 256) {
    int idx = base + i;
    if (idx < n) s += cur[idx];
  }
  int tid = threadIdx.x;
  lds[tid] = s;
  __syncthreads();
  for (int off = 128; off > 0; off >>= 1) {
    if (tid < off) lds[tid] += lds[tid + off];
    __syncthreads();
  }
  if (tid == 0) bsum[type * MAXNB + blockIdx.x] = lds[0];
}

__global__ __launch_bounds__(64) void k_scan2(int* __restrict__ bsum) {
  int t = threadIdx.x;
  if (t < 4) {
    int run = 0;
    for (int i = 0; i < MAXNB; ++i) {
      int v = bsum[t * MAXNB + i];
      bsum[t * MAXNB + i] = run;
      run += v;
    }
  }
}

__global__ __launch_bounds__(256) void k_scan3(CsrPtrs p,
                                               const int* __restrict__ bsum,
                                               int E) {
  __shared__ int lds[256];
  int type = blockIdx.y;
  int* cur = p.cur[type];
  int* rp = p.rp[type];
  int n = p.n[type];
  int tid = threadIdx.x;
  if (blockIdx.x == 0 && tid == 0) rp[n] = E;
  int t0 = blockIdx.x * 4096 + tid * 16;
  int loc[16];
  int s = 0;
#pragma unroll
  for (int j = 0; j < 16; ++j) {
    int idx = t0 + j;
    int v = (idx < n) ? cur[idx] : 0;
    loc[j] = s;
    s += v;
  }
  lds[tid] = s;
  __syncthreads();
  for (int off = 1; off < 256; off <<= 1) {
    int v = (tid >= off) ? lds[tid - off] : 0;
    __syncthreads();
    lds[tid] += v;
    __syncthreads();
  }
  int off0 = bsum[type * MAXNB + blockIdx.x] + ((tid == 0) ? 0 : lds[tid - 1]);
#pragma unroll
  for (int j = 0; j < 16; ++j) {
    int idx = t0 + j;
    if (idx < n) {
      int v = off0 + loc[j];
      rp[idx] = v;
      cur[idx] = v;  // cursor becomes fill position
    }
  }
}

// payload = src | (combo << 16)
__global__ __launch_bounds__(256) void k_fill4(EdgeArr A, int E) {
  int t = blockIdx.y;
  int e = blockIdx.x * 256 + threadIdx.x;
  if (e >= E) return;
  const int* ei = A.ei[t];
  const int* ea = A.ea[t];
  int dst = ei[E + e];
  int src = ei[e];
  int combo = ea[2 * e] * 3 + ea[2 * e + 1];
  int pos = atomicAdd(&A.cur[t][dst], 1);
  A.pay[t][pos] = src | (combo << 16);
}

// ---------------------------------------------------------------------------
// CSR gather over bf16 h with optional fused BN+ReLU on read.
// MODE 0: init = 0;  MODE 1: init = h(g) + es;  MODE 2: init = 2.1*h(g) + es
template <int MODE, bool NORM>
__global__ __launch_bounds__(256) void k_gather(
    const unsigned short* __restrict__ hsrc,
    const unsigned short* __restrict__ hinit, const int* __restrict__ rowptr,
    const int* __restrict__ payload, const float* __restrict__ etbl,
    const float* __restrict__ bnp, unsigned short* __restrict__ agg, int n) {
  __shared__ float et[10 * D];
  for (int i = threadIdx.x; i < 10 * D; i += 256) et[i] = etbl[i];
  __syncthreads();
  int g = blockIdx.x * 8 + (threadIdx.x >> 5);
  if (g >= n) return;
  int l = threadIdx.x & 31;
  int c = l * 4;
  float4 scv, shv;
  if (NORM) {
    scv = *(const float4*)(bnp + c);
    shv = *(const float4*)(bnp + D + c);
  }

  auto xform = [&](ushort4 hv) {
    float4 r;
    r.x = bf2f(hv.x); r.y = bf2f(hv.y); r.z = bf2f(hv.z); r.w = bf2f(hv.w);
    if (NORM) {
      r.x = fmaxf(fmaf(r.x, scv.x, shv.x), 0.f);
      r.y = fmaxf(fmaf(r.y, scv.y, shv.y), 0.f);
      r.z = fmaxf(fmaf(r.z, scv.z, shv.z), 0.f);
      r.w = fmaxf(fmaf(r.w, scv.w, shv.w), 0.f);
    }
    return r;
  };
  auto fetch = [&](int p) {
    int src = p & 0xFFFF;
    int combo = p >> 16;
    float4 h = xform(*(const ushort4*)(hsrc + (size_t)src * D + c));
    float4 r;
    r.x = h.x + et[combo * D + c + 0];
    r.y = h.y + et[combo * D + c + 1];
    r.z = h.z + et[combo * D + c + 2];
    r.w = h.w + et[combo * D + c + 3];
    return r;
  };

  float4 acc, acc2 = make_float4(0.f, 0.f, 0.f, 0.f);
  if (MODE == 0) {
    acc = make_float4(0.f, 0.f, 0.f, 0.f);
  } else {
    float4 h = xform(*(const ushort4*)(hinit + (size_t)g * D + c));
    float sc = (MODE == 2) ? 2.1f : 1.0f;
    acc.x = sc * h.x + et[9 * D + c + 0];
    acc.y = sc * h.y + et[9 * D + c + 1];
    acc.z = sc * h.z + et[9 * D + c + 2];
    acc.w = sc * h.w + et[9 * D + c + 3];
  }

  int e0 = rowptr[g], e1 = rowptr[g + 1];
  int e = e0;
  while (e < e1) {
    int cnt = min(32, e1 - e);
    int pv = (e + l < e1) ? payload[e + l] : 0;  // coalesced chunk
    int j = 0;
    for (; j + 1 < cnt; j += 2) {
      int p0 = __shfl(pv, j, 32);
      int p1 = __shfl(pv, j + 1, 32);
      float4 t0 = fetch(p0);
      float4 t1 = fetch(p1);
      acc.x += t0.x; acc.y += t0.y; acc.z += t0.z; acc.w += t0.w;
      acc2.x += t1.x; acc2.y += t1.y; acc2.z += t1.z; acc2.w += t1.w;
    }
    if (j < cnt) {
      float4 t = fetch(__shfl(pv, j, 32));
      acc.x += t.x; acc.y += t.y; acc.z += t.z; acc.w += t.w;
    }
    e += cnt;
  }
  acc.x += acc2.x; acc.y += acc2.y; acc.z += acc2.z; acc.w += acc2.w;
  ushort4 o;
  o.x = f2bf(acc.x); o.y = f2bf(acc.y); o.z = f2bf(acc.z); o.w = f2bf(acc.w);
  *(ushort4*)(agg + (size_t)g * D + c) = o;
}

// ---------------------------------------------------------------------------
// bf16 MFMA GEMM, occupancy-tiled: 512 threads = 8 waves; wave (rg,ch) does
// rows [blk*64+rg*16, +16) x cols [ch*NCOLS/2, +NCOLS/2). Fragment layouts:
//   A: row=l&15, k=(l>>4)*8+j   B: col=l&15, k=(l>>4)*8+j   D: col=l&15, row=(l>>4)*4+r
template <int KK, int NFW>
__device__ __forceinline__ void kloop(const unsigned short* __restrict__ A,
                                      const unsigned short* __restrict__ Wt,
                                      int arow, int colbase, int lr, int lk,
                                      f32x4 (&acc)[NFW]) {
#pragma unroll
  for (int k0 = 0; k0 < KK; k0 += 32) {
    bf16x8 a = *(const bf16x8*)(A + (size_t)arow * KK + k0 + lk * 8);
#pragma unroll
    for (int nf = 0; nf < NFW; ++nf) {
      bf16x8 b =
          *(const bf16x8*)(Wt + (size_t)(colbase + nf * 16 + lr) * KK + k0 + lk * 8);
      acc[nf] = __builtin_amdgcn_mfma_f32_16x16x32_bf16(a, b, acc[nf], 0, 0, 0);
    }
  }
}

template <int NCOLS, int K1, int K2, bool RELU, bool STATS, bool OBF16>
__global__ __launch_bounds__(512) void gemm_mfma(
    const unsigned short* __restrict__ A1, const unsigned short* __restrict__ Wt1,
    const unsigned short* __restrict__ A2, const unsigned short* __restrict__ Wt2,
    const float* __restrict__ bias, void* __restrict__ Cv, int M,
    float* __restrict__ stats) {
  constexpr int NFW = NCOLS / 32;  // frags per wave (half of NCOLS)
  __shared__ float red[STATS ? 8 * NCOLS : 1];
  int tid = threadIdx.x;
  int w = tid >> 6, l = tid & 63;
  int rg = w >> 1, ch = w & 1;
  int lr = l & 15, lk = l >> 4;
  int row0 = blockIdx.x * 64 + rg * 16;
  int colbase = ch * (NCOLS / 2);
  int arow = min(row0 + lr, M - 1);  // clamp OOB loads; stores guarded

  f32x4 acc[NFW];
#pragma unroll
  for (int nf = 0; nf < NFW; ++nf) acc[nf] = (f32x4)(0.f);

  kloop<K1, NFW>(A1, Wt1, arow, colbase, lr, lk, acc);
  if constexpr (K2 > 0) kloop<K2, NFW>(A2, Wt2, arow, colbase, lr, lk, acc);

  float bv[NFW];
#pragma unroll
  for (int nf = 0; nf < NFW; ++nf) bv[nf] = bias[colbase + nf * 16 + lr];

  float colS[NFW], colQ[NFW];
#pragma unroll
  for (int nf = 0; nf < NFW; ++nf) { colS[nf] = 0.f; colQ[nf] = 0.f; }

  float* Cf = (float*)Cv;
  unsigned short* Cb = (unsigned short*)Cv;
#pragma unroll
  for (int r = 0; r < 4; ++r) {
    int row = row0 + lk * 4 + r;
    bool ok = row < M;
#pragma unroll
    for (int nf = 0; nf < NFW; ++nf) {
      int col = colbase + nf * 16 + lr;
      float v = acc[nf][r] + bv[nf];
      if (RELU) v = fmaxf(v, 0.f);
      if (ok) {
        if (OBF16)
          Cb[(size_t)row * NCOLS + col] = f2bf(v);
        else
          Cf[(size_t)row * NCOLS + col] = v;
        if (STATS) { colS[nf] += v; colQ[nf] += v * v; }
      }
    }
  }

  if constexpr (STATS) {
#pragma unroll
    for (int nf = 0; nf < NFW; ++nf) {
      float s = colS[nf], q = colQ[nf];
      s += __shfl_xor(s, 16); q += __shfl_xor(q, 16);
      s += __shfl_xor(s, 32); q += __shfl_xor(q, 32);
      if (lk == 0) {
        red[rg * NCOLS + colbase + nf * 16 + lr] = s;
        red[4 * NCOLS + rg * NCOLS + colbase + nf * 16 + lr] = q;
      }
    }
    __syncthreads();
    if (tid < NCOLS) {
      float s = 0.f, q = 0.f;
#pragma unroll
      for (int j = 0; j < 4; ++j) {
        s += red[j * NCOLS + tid];
        q += red[4 * NCOLS + j * NCOLS + tid];
      }
      atomicAdd(&stats[tid], s);
      atomicAdd(&stats[D + tid], q);
    }
  }
}

// ---------------------------------------------------------------------------
// stats -> (scale, shift) for both node types
__global__ __launch_bounds__(256) void k_bnprep(const float* __restrict__ stats,
                                                const float* __restrict__ gamma,
                                                const float* __restrict__ beta,
                                                float* __restrict__ bnp0,
                                                float* __restrict__ bnp1,
                                                float invM0, float invM1) {
  int i = threadIdx.x;
  if (i < 128) {
    float mu = stats[i] * invM0;
    float var = stats[D + i] * invM0 - mu * mu;
    float sc = rsqrtf(var + BN_EPS) * gamma[i];
    bnp0[i] = sc;
    bnp0[D + i] = beta[i] - mu * sc;
  } else {
    int d = i - 128;
    float mu = stats[2 * D + d] * invM1;
    float var = stats[3 * D + d] * invM1 - mu * mu;
    float sc = rsqrtf(var + BN_EPS) * gamma[d];
    bnp1[d] = sc;
    bnp1[D + d] = beta[d] - mu * sc;
  }
}

// final-layer BN (no relu), fp32 in place
__global__ __launch_bounds__(256) void k_bnfin(float* __restrict__ X, int M,
                                               const float* __restrict__ bnp) {
  int idx = blockIdx.x * 256 + threadIdx.x;
  int i = idx >> 5, c4 = idx & 31;
  if (i >= M) return;
  float4 v = *(float4*)(X + (size_t)i * D + c4 * 4);
  float4 sc = *(const float4*)(bnp + c4 * 4);
  float4 sh = *(const float4*)(bnp + D + c4 * 4);
  float4 o;
  o.x = fmaf(v.x, sc.x, sh.x); o.y = fmaf(v.y, sc.y, sh.y);
  o.z = fmaf(v.z, sc.z, sh.z); o.w = fmaf(v.w, sc.w, sh.w);
  *(float4*)(X + (size_t)i * D + c4 * 4) = o;
}

// ---------------------------------------------------------------------------
extern "C" void kernel_launch(void* const* d_in, const int* in_sizes, int n_in,
                              void* d_out, int out_size, void* d_ws,
                              size_t ws_size, hipStream_t stream) {
  const int* x0 = (const int*)d_in[0];
  const int* x1 = (const int*)d_in[1];
  const int* ei101 = (const int*)d_in[2];
  const int* ea101 = (const int*)d_in[3];
  const int* ei110 = (const int*)d_in[4];
  const int* ea110 = (const int*)d_in[5];
  const int* ei021 = (const int*)d_in[6];
  const int* ea021 = (const int*)d_in[7];
  const int* ei030 = (const int*)d_in[8];
  const int* ea030 = (const int*)d_in[9];
  const float* x_emb1 = (const float*)d_in[10];
  const float* x_emb2 = (const float*)d_in[11];
  const float* e_emb1 = (const float*)d_in[12];
  const float* e_emb2 = (const float*)d_in[13];
  const float* gin_w1 = (const float*)d_in[14];
  const float* gin_b1 = (const float*)d_in[15];
  const float* gin_w2 = (const float*)d_in[16];
  const float* gin_b2 = (const float*)d_in[17];
  const float* w110 = (const float*)d_in[18];
  const float* b110 = (const float*)d_in[19];
  const float* w021 = (const float*)d_in[20];
  const float* b021 = (const float*)d_in[21];
  const float* w030 = (const float*)d_in[22];
  const float* b030 = (const float*)d_in[23];
  const float* bn_gamma = (const float*)d_in[24];
  const float* bn_beta = (const float*)d_in[25];

  int n0 = in_sizes[0] / 2, n1 = in_sizes[1] / 2;
  int E = in_sizes[2] / 2;
  int nmax = n0 > n1 ? n0 : n1;

  float* h0f = (float*)d_out;
  float* h1f = h0f + (size_t)n0 * D;

  // ---- workspace layout ----
  char* p = (char*)d_ws;
  auto alloc = [&](size_t bytes) {
    char* r = p;
    p += (bytes + 63) & ~(size_t)63;
    return r;
  };
  unsigned short* h0r = (unsigned short*)alloc((size_t)n0 * D * 2);
  unsigned short* h1r = (unsigned short*)alloc((size_t)n1 * D * 2);
  unsigned short* z1b = (unsigned short*)alloc((size_t)n1 * D * 2);
  unsigned short* a021b = (unsigned short*)alloc((size_t)n1 * D * 2);
  unsigned short* a110b = (unsigned short*)alloc((size_t)n0 * D * 2);
  unsigned short* a030b = (unsigned short*)alloc((size_t)n0 * D * 2);
  unsigned short* hiddenb = (unsigned short*)alloc((size_t)n1 * 256 * 2);
  float* etbl = (float*)alloc(10 * D * 4);
  float* stats = (float*)alloc(4 * D * 4);
  float* bnp0 = (float*)alloc(2 * D * 4);
  float* bnp1 = (float*)alloc(2 * D * 4);
  unsigned short* wt110 = (unsigned short*)alloc(128 * 128 * 2);
  unsigned short* wt030 = (unsigned short*)alloc(128 * 128 * 2);
  unsigned short* wt021 = (unsigned short*)alloc(128 * 128 * 2);
  unsigned short* wtg1 = (unsigned short*)alloc(256 * 128 * 2);  // [N=256][K=128]
  unsigned short* wtg2 = (unsigned short*)alloc(128 * 256 * 2);  // [N=128][K=256]
  float* bias0 = (float*)alloc(128 * 4);
  float* biash = (float*)alloc(256 * 4);
  float* bias1 = (float*)alloc(128 * 4);

  EdgeArr EA;
  CsrPtrs cp;
  const int* eis[4] = {ei101, ei021, ei110, ei030};
  const int* eas[4] = {ea101, ea021, ea110, ea030};
  int ndst[4] = {n1, n1, n0, n0};
  for (int t = 0; t < 4; ++t) {
    cp.rp[t] = (int*)alloc((size_t)(nmax + 1) * 4);
    cp.cur[t] = (int*)alloc((size_t)nmax * 4);
    EA.pay[t] = (int*)alloc((size_t)E * 4);
    cp.n[t] = ndst[t];
    EA.ei[t] = eis[t];
    EA.ea[t] = eas[t];
    EA.cur[t] = cp.cur[t];
  }
  int* bsum = (int*)alloc(4 * MAXNB * 4);

  dim3 b256(256);
  int eBlocks = (E + 255) / 256;

  // one-time: tables, embeddings, weight prep, CSR build
  k_etbl<<<5, b256, 0, stream>>>(e_emb1, e_emb2, etbl);
  k_embed<<<(n0 * 32 + 255) / 256, b256, 0, stream>>>(x0, x_emb1, x_emb2, h0r, n0);
  k_embed<<<(n1 * 32 + 255) / 256, b256, 0, stream>>>(x1, x_emb1, x_emb2, h1r, n1);
  k_wprep<<<64, b256, 0, stream>>>(w110, wt110, 128, 128, 0.05f);
  k_wprep<<<64, b256, 0, stream>>>(w030, wt030, 128, 128, 0.05f);
  k_wprep<<<64, b256, 0, stream>>>(w021, wt021, 128, 128, 0.05f);
  k_wprep<<<128, b256, 0, stream>>>(gin_w1, wtg1, 128, 256, 1.0f);
  k_wprep<<<128, b256, 0, stream>>>(gin_w2, wtg2, 256, 128, 0.5f);
  k_bprep<<<1, b256, 0, stream>>>(b110, b030, gin_b1, gin_b2, b021, bias0, biash, bias1);

  for (int t = 0; t < 4; ++t)
    hipMemsetAsync(cp.cur[t], 0, (size_t)ndst[t] * sizeof(int), stream);
  k_hist4<<<dim3(eBlocks, 4), b256, 0, stream>>>(EA, E);
  hipMemsetAsync(bsum, 0, 4 * MAXNB * sizeof(int), stream);
  int nb = (nmax + 4095) / 4096;
  k_scan1<<<dim3(nb, 4), b256, 0, stream>>>(cp, bsum);
  k_scan2<<<1, dim3(64), 0, stream>>>(bsum);
  k_scan3<<<dim3(nb, 4), b256, 0, stream>>>(cp, bsum, E);
  k_fill4<<<dim3(eBlocks, 4), b256, 0, stream>>>(EA, E);

  int gB0 = (n0 + 7) / 8, gB1 = (n1 + 7) / 8;
  int mB0 = (n0 + 63) / 64, mB1 = (n1 + 63) / 64;
  dim3 b512(512);

  for (int layer = 0; layer < 3; ++layer) {
    // aggregations: BN+ReLU of h folded into the read (layers 1,2)
    if (layer == 0) {
      k_gather<2, false><<<gB1, b256, 0, stream>>>(h1r, h1r, cp.rp[0], EA.pay[0], etbl, nullptr, z1b, n1);
      k_gather<0, false><<<gB1, b256, 0, stream>>>(h0r, nullptr, cp.rp[1], EA.pay[1], etbl, nullptr, a021b, n1);
      k_gather<0, false><<<gB0, b256, 0, stream>>>(h1r, nullptr, cp.rp[2], EA.pay[2], etbl, nullptr, a110b, n0);
      k_gather<1, false><<<gB0, b256, 0, stream>>>(h0r, h0r, cp.rp[3], EA.pay[3], etbl, nullptr, a030b, n0);
    } else {
      k_gather<2, true><<<gB1, b256, 0, stream>>>(h1r, h1r, cp.rp[0], EA.pay[0], etbl, bnp1, z1b, n1);
      k_gather<0, true><<<gB1, b256, 0, stream>>>(h0r, nullptr, cp.rp[1], EA.pay[1], etbl, bnp0, a021b, n1);
      k_gather<0, true><<<gB0, b256, 0, stream>>>(h1r, nullptr, cp.rp[2], EA.pay[2], etbl, bnp1, a110b, n0);
      k_gather<1, true><<<gB0, b256, 0, stream>>>(h0r, h0r, cp.rp[3], EA.pay[3], etbl, bnp0, a030b, n0);
    }

    hipMemsetAsync(stats, 0, 4 * D * sizeof(float), stream);

    if (layer < 2) {
      // raw (pre-BN) bf16 outputs into h0r/h1r
      gemm_mfma<128, 128, 128, false, true, true><<<mB0, b512, 0, stream>>>(
          a110b, wt110, a030b, wt030, bias0, h0r, n0, stats);
      gemm_mfma<256, 128, 0, true, false, true><<<mB1, b512, 0, stream>>>(
          z1b, wtg1, nullptr, nullptr, biash, hiddenb, n1, nullptr);
      gemm_mfma<128, 256, 128, false, true, true><<<mB1, b512, 0, stream>>>(
          hiddenb, wtg2, a021b, wt021, bias1, h1r, n1, stats + 2 * D);
    } else {
      // final layer: raw fp32 straight into d_out, BN applied in place after
      gemm_mfma<128, 128, 128, false, true, false><<<mB0, b512, 0, stream>>>(
          a110b, wt110, a030b, wt030, bias0, h0f, n0, stats);
      gemm_mfma<256, 128, 0, true, false, true><<<mB1, b512, 0, stream>>>(
          z1b, wtg1, nullptr, nullptr, biash, hiddenb, n1, nullptr);
      gemm_mfma<128, 256, 128, false, true, false><<<mB1, b512, 0, stream>>>(
          hiddenb, wtg2, a021b, wt021, bias1, h1f, n1, stats + 2 * D);
    }

    k_bnprep<<<1, b256, 0, stream>>>(stats, bn_gamma + layer * D,
                                     bn_beta + layer * D, bnp0, bnp1,
                                     1.0f / n0, 1.0f / n1);
    if (layer == 2) {
      k_bnfin<<<(n0 * 32 + 255) / 256, b256, 0, stream>>>(h0f, n0, bnp0);
      k_bnfin<<<(n1 * 32 + 255) / 256, b256, 0, stream>>>(h1f, n1, bnp1);
    }
  }
}

// Round 7
// 796.961 us; speedup vs baseline: 9.4717x; 1.1543x over previous
//
#include <hip/hip_runtime.h>

#define D 128
#define BN_EPS 1e-5f
#define MAXNB 16  // max scan blocks per type (n <= 65536)

typedef __attribute__((ext_vector_type(8))) short bf16x8;
typedef __attribute__((ext_vector_type(4))) float f32x4;

__device__ __forceinline__ unsigned short f2bf(float x) {
  unsigned u = __float_as_uint(x);
  u += 0x7FFF + ((u >> 16) & 1);  // round-to-nearest-even
  return (unsigned short)(u >> 16);
}
__device__ __forceinline__ float bf2f(unsigned short u) {
  return __uint_as_float((unsigned)u << 16);
}

// ---------------------------------------------------------------------------
// edge-attr combo table: 9 combos + self-loop (4,0) at slot 9
__global__ __launch_bounds__(256) void k_etbl(const float* __restrict__ e1,
                                              const float* __restrict__ e2,
                                              float* __restrict__ etbl) {
  int idx = blockIdx.x * 256 + threadIdx.x;
  if (idx < 9 * D) {
    int combo = idx / D, c = idx % D;
    etbl[idx] = e1[(combo / 3) * D + c] + e2[(combo % 3) * D + c];
  } else if (idx < 10 * D) {
    int c = idx - 9 * D;
    etbl[idx] = e1[4 * D + c] + e2[c];
  }
}

// node embedding -> bf16 h
__global__ __launch_bounds__(256) void k_embed(const int* __restrict__ x,
                                               const float* __restrict__ emb1,
                                               const float* __restrict__ emb2,
                                               unsigned short* __restrict__ out,
                                               int n) {
  int idx = blockIdx.x * 256 + threadIdx.x;
  if (idx >= n * 32) return;
  int node = idx >> 5, c4 = idx & 31;
  int i1 = x[2 * node], i2 = x[2 * node + 1];
  float4 v1 = *(const float4*)(emb1 + (size_t)i1 * D + c4 * 4);
  float4 v2 = *(const float4*)(emb2 + (size_t)i2 * D + c4 * 4);
  ushort4 o;
  o.x = f2bf(v1.x + v2.x); o.y = f2bf(v1.y + v2.y);
  o.z = f2bf(v1.z + v2.z); o.w = f2bf(v1.w + v2.w);
  *(ushort4*)(out + (size_t)node * D + c4 * 4) = o;
}

// ---------------------------------------------------------------------------
// weight prep: Wt[n][k] = bf16(W[k][n] * scale)
__global__ __launch_bounds__(256) void k_wprep(const float* __restrict__ W,
                                               unsigned short* __restrict__ Wt,
                                               int K, int N, float scale) {
  int idx = blockIdx.x * 256 + threadIdx.x;
  if (idx >= K * N) return;
  int n = idx / K, k = idx - n * K;
  Wt[idx] = f2bf(W[(size_t)k * N + n] * scale);
}

__global__ __launch_bounds__(256) void k_bprep(
    const float* __restrict__ b110, const float* __restrict__ b030,
    const float* __restrict__ gb1, const float* __restrict__ gb2,
    const float* __restrict__ b021, float* __restrict__ bias0,
    float* __restrict__ biash, float* __restrict__ bias1) {
  int i = threadIdx.x;
  if (i < 128) {
    bias0[i] = 0.05f * (b110[i] + b030[i]);
    bias1[i] = 0.5f * gb2[i] + 0.05f * b021[i];
  }
  biash[i] = gb1[i];
}

// ---------------------------------------------------------------------------
// CSR build (all 4 edge types via grid.y)
struct EdgeArr {
  const int* ei[4];
  const int* ea[4];
  int* cur[4];
  int* pay[4];
};
struct CsrPtrs {
  int* cur[4];
  int* rp[4];
  int n[4];
};

__global__ __launch_bounds__(256) void k_hist4(EdgeArr A, int E) {
  int t = blockIdx.y;
  int e = blockIdx.x * 256 + threadIdx.x;
  if (e >= E) return;
  atomicAdd(&A.cur[t][A.ei[t][E + e]], 1);
}

__global__ __launch_bounds__(256) void k_scan1(CsrPtrs p, int* __restrict__ bsum) {
  __shared__ int lds[256];
  int type = blockIdx.y;
  const int* cur = p.cur[type];
  int n = p.n[type];
  int base = blockIdx.x * 4096;
  int s = 0;
  for (int i = threadIdx.x; i < 4096; i += 256) {
    int idx = base + i;
    if (idx < n) s += cur[idx];
  }
  int tid = threadIdx.x;
  lds[tid] = s;
  __syncthreads();
  for (int off = 128; off > 0; off >>= 1) {
    if (tid < off) lds[tid] += lds[tid + off];
    __syncthreads();
  }
  if (tid == 0) bsum[type * MAXNB + blockIdx.x] = lds[0];
}

__global__ __launch_bounds__(64) void k_scan2(int* __restrict__ bsum) {
  int t = threadIdx.x;
  if (t < 4) {
    int run = 0;
    for (int i = 0; i < MAXNB; ++i) {
      int v = bsum[t * MAXNB + i];
      bsum[t * MAXNB + i] = run;
      run += v;
    }
  }
}

__global__ __launch_bounds__(256) void k_scan3(CsrPtrs p,
                                               const int* __restrict__ bsum,
                                               int E) {
  __shared__ int lds[256];
  int type = blockIdx.y;
  int* cur = p.cur[type];
  int* rp = p.rp[type];
  int n = p.n[type];
  int tid = threadIdx.x;
  if (blockIdx.x == 0 && tid == 0) rp[n] = E;
  int t0 = blockIdx.x * 4096 + tid * 16;
  int loc[16];
  int s = 0;
#pragma unroll
  for (int j = 0; j < 16; ++j) {
    int idx = t0 + j;
    int v = (idx < n) ? cur[idx] : 0;
    loc[j] = s;
    s += v;
  }
  lds[tid] = s;
  __syncthreads();
  for (int off = 1; off < 256; off <<= 1) {
    int v = (tid >= off) ? lds[tid - off] : 0;
    __syncthreads();
    lds[tid] += v;
    __syncthreads();
  }
  int off0 = bsum[type * MAXNB + blockIdx.x] + ((tid == 0) ? 0 : lds[tid - 1]);
#pragma unroll
  for (int j = 0; j < 16; ++j) {
    int idx = t0 + j;
    if (idx < n) {
      int v = off0 + loc[j];
      rp[idx] = v;
      cur[idx] = v;  // cursor becomes fill position
    }
  }
}

// payload = src | (combo << 16)
__global__ __launch_bounds__(256) void k_fill4(EdgeArr A, int E) {
  int t = blockIdx.y;
  int e = blockIdx.x * 256 + threadIdx.x;
  if (e >= E) return;
  const int* ei = A.ei[t];
  const int* ea = A.ea[t];
  int dst = ei[E + e];
  int src = ei[e];
  int combo = ea[2 * e] * 3 + ea[2 * e + 1];
  int pos = atomicAdd(&A.cur[t][dst], 1);
  A.pay[t][pos] = src | (combo << 16);
}

// ---------------------------------------------------------------------------
// CSR gather over bf16 h with optional fused BN+ReLU on read.
// MODE 0: init = 0;  MODE 1: init = h(g) + es;  MODE 2: init = 2.1*h(g) + es
template <int MODE, bool NORM>
__global__ __launch_bounds__(256) void k_gather(
    const unsigned short* __restrict__ hsrc,
    const unsigned short* __restrict__ hinit, const int* __restrict__ rowptr,
    const int* __restrict__ payload, const float* __restrict__ etbl,
    const float* __restrict__ bnp, unsigned short* __restrict__ agg, int n) {
  __shared__ float et[10 * D];
  for (int i = threadIdx.x; i < 10 * D; i += 256) et[i] = etbl[i];
  __syncthreads();
  int g = blockIdx.x * 8 + (threadIdx.x >> 5);
  if (g >= n) return;
  int l = threadIdx.x & 31;
  int c = l * 4;
  float4 scv, shv;
  if (NORM) {
    scv = *(const float4*)(bnp + c);
    shv = *(const float4*)(bnp + D + c);
  }

  auto xform = [&](ushort4 hv) {
    float4 r;
    r.x = bf2f(hv.x); r.y = bf2f(hv.y); r.z = bf2f(hv.z); r.w = bf2f(hv.w);
    if (NORM) {
      r.x = fmaxf(fmaf(r.x, scv.x, shv.x), 0.f);
      r.y = fmaxf(fmaf(r.y, scv.y, shv.y), 0.f);
      r.z = fmaxf(fmaf(r.z, scv.z, shv.z), 0.f);
      r.w = fmaxf(fmaf(r.w, scv.w, shv.w), 0.f);
    }
    return r;
  };
  auto fetch = [&](int p) {
    int src = p & 0xFFFF;
    int combo = p >> 16;
    float4 h = xform(*(const ushort4*)(hsrc + (size_t)src * D + c));
    float4 r;
    r.x = h.x + et[combo * D + c + 0];
    r.y = h.y + et[combo * D + c + 1];
    r.z = h.z + et[combo * D + c + 2];
    r.w = h.w + et[combo * D + c + 3];
    return r;
  };

  float4 acc, acc2 = make_float4(0.f, 0.f, 0.f, 0.f);
  if (MODE == 0) {
    acc = make_float4(0.f, 0.f, 0.f, 0.f);
  } else {
    float4 h = xform(*(const ushort4*)(hinit + (size_t)g * D + c));
    float sc = (MODE == 2) ? 2.1f : 1.0f;
    acc.x = sc * h.x + et[9 * D + c + 0];
    acc.y = sc * h.y + et[9 * D + c + 1];
    acc.z = sc * h.z + et[9 * D + c + 2];
    acc.w = sc * h.w + et[9 * D + c + 3];
  }

  int e0 = rowptr[g], e1 = rowptr[g + 1];
  int e = e0;
  while (e < e1) {
    int cnt = min(32, e1 - e);
    int pv = (e + l < e1) ? payload[e + l] : 0;  // coalesced chunk
    int j = 0;
    for (; j + 1 < cnt; j += 2) {
      int p0 = __shfl(pv, j, 32);
      int p1 = __shfl(pv, j + 1, 32);
      float4 t0 = fetch(p0);
      float4 t1 = fetch(p1);
      acc.x += t0.x; acc.y += t0.y; acc.z += t0.z; acc.w += t0.w;
      acc2.x += t1.x; acc2.y += t1.y; acc2.z += t1.z; acc2.w += t1.w;
    }
    if (j < cnt) {
      float4 t = fetch(__shfl(pv, j, 32));
      acc.x += t.x; acc.y += t.y; acc.z += t.z; acc.w += t.w;
    }
    e += cnt;
  }
  acc.x += acc2.x; acc.y += acc2.y; acc.z += acc2.z; acc.w += acc2.w;
  ushort4 o;
  o.x = f2bf(acc.x); o.y = f2bf(acc.y); o.z = f2bf(acc.z); o.w = f2bf(acc.w);
  *(ushort4*)(agg + (size_t)g * D + c) = o;
}

// ---------------------------------------------------------------------------
// B-stationary bf16 MFMA GEMM.
// Block = 256 thr (4 waves), tile 64 rows x NCOLS. Wave w: all 64 rows x
// NCOLS/4 cols, with its whole B panel in registers (loaded once from L2).
// Steady state per k-step: 4 independent A loads (L1-resident, shared across
// the block's 4 waves) + CF*4 MFMAs. Fragment layouts (verified r5/r6):
//   A: row=l&15, k=(l>>4)*8+j   B: col=l&15, k=(l>>4)*8+j   D: col=l&15, row=(l>>4)*4+r
template <int NCOLS, int K1, int K2, bool RELU, bool STATS, bool OBF16>
__global__ __launch_bounds__(256) void gemm_breg(
    const unsigned short* __restrict__ A1, const unsigned short* __restrict__ Wt1,
    const unsigned short* __restrict__ A2, const unsigned short* __restrict__ Wt2,
    const float* __restrict__ bias, void* __restrict__ Cv, int M,
    float* __restrict__ stats) {
  constexpr int WC = NCOLS / 4;   // cols per wave
  constexpr int CF = WC / 16;     // col frags per wave
  constexpr int KF1 = K1 / 32;
  constexpr int KF2 = (K2 > 0) ? (K2 / 32) : 1;

  int tid = threadIdx.x;
  int w = tid >> 6, l = tid & 63;
  int lr = l & 15, lk = l >> 4;
  int colbase = w * WC;
  int row0 = blockIdx.x * 64;

  f32x4 acc[4][CF];
#pragma unroll
  for (int rf = 0; rf < 4; ++rf)
#pragma unroll
    for (int cf = 0; cf < CF; ++cf) acc[rf][cf] = (f32x4)(0.f);

  // ---- source 1 ----
  {
    const unsigned short* ap[4];
#pragma unroll
    for (int rf = 0; rf < 4; ++rf) {
      int r = row0 + rf * 16 + lr;
      if (r > M - 1) r = M - 1;  // clamp OOB loads; stores guarded below
      ap[rf] = A1 + (size_t)r * K1 + lk * 8;
    }
    bf16x8 B[CF][KF1];
#pragma unroll
    for (int cf = 0; cf < CF; ++cf)
#pragma unroll
      for (int kf = 0; kf < KF1; ++kf)
        B[cf][kf] = *(const bf16x8*)(Wt1 + (size_t)(colbase + cf * 16 + lr) * K1 +
                                     kf * 32 + lk * 8);
#pragma unroll
    for (int kf = 0; kf < KF1; ++kf) {
      bf16x8 a[4];
#pragma unroll
      for (int rf = 0; rf < 4; ++rf) a[rf] = *(const bf16x8*)(ap[rf] + kf * 32);
#pragma unroll
      for (int rf = 0; rf < 4; ++rf)
#pragma unroll
        for (int cf = 0; cf < CF; ++cf)
          acc[rf][cf] = __builtin_amdgcn_mfma_f32_16x16x32_bf16(a[rf], B[cf][kf],
                                                                acc[rf][cf], 0, 0, 0);
    }
  }
  // ---- source 2 ----
  if constexpr (K2 > 0) {
    const unsigned short* ap[4];
#pragma unroll
    for (int rf = 0; rf < 4; ++rf) {
      int r = row0 + rf * 16 + lr;
      if (r > M - 1) r = M - 1;
      ap[rf] = A2 + (size_t)r * K2 + lk * 8;
    }
    bf16x8 B[CF][KF2];
#pragma unroll
    for (int cf = 0; cf < CF; ++cf)
#pragma unroll
      for (int kf = 0; kf < KF2; ++kf)
        B[cf][kf] = *(const bf16x8*)(Wt2 + (size_t)(colbase + cf * 16 + lr) * K2 +
                                     kf * 32 + lk * 8);
#pragma unroll
    for (int kf = 0; kf < KF2; ++kf) {
      bf16x8 a[4];
#pragma unroll
      for (int rf = 0; rf < 4; ++rf) a[rf] = *(const bf16x8*)(ap[rf] + kf * 32);
#pragma unroll
      for (int rf = 0; rf < 4; ++rf)
#pragma unroll
        for (int cf = 0; cf < CF; ++cf)
          acc[rf][cf] = __builtin_amdgcn_mfma_f32_16x16x32_bf16(a[rf], B[cf][kf],
                                                                acc[rf][cf], 0, 0, 0);
    }
  }

  // ---- epilogue ----
  float bv[CF];
#pragma unroll
  for (int cf = 0; cf < CF; ++cf) bv[cf] = bias[colbase + cf * 16 + lr];

  float colS[CF], colQ[CF];
#pragma unroll
  for (int cf = 0; cf < CF; ++cf) { colS[cf] = 0.f; colQ[cf] = 0.f; }

  float* Cf = (float*)Cv;
  unsigned short* Cb = (unsigned short*)Cv;
#pragma unroll
  for (int rf = 0; rf < 4; ++rf) {
#pragma unroll
    for (int r = 0; r < 4; ++r) {
      int row = row0 + rf * 16 + lk * 4 + r;
      bool ok = row < M;
#pragma unroll
      for (int cf = 0; cf < CF; ++cf) {
        int col = colbase + cf * 16 + lr;
        float v = acc[rf][cf][r] + bv[cf];
        if (RELU) v = fmaxf(v, 0.f);
        if (ok) {
          if (OBF16)
            Cb[(size_t)row * NCOLS + col] = f2bf(v);
          else
            Cf[(size_t)row * NCOLS + col] = v;
          if (STATS) { colS[cf] += v; colQ[cf] += v * v; }
        }
      }
    }
  }

  if constexpr (STATS) {
    // each column owned by exactly one wave of this block: shfl-reduce over
    // the 4 lk row-groups, then one atomic per column per block
#pragma unroll
    for (int cf = 0; cf < CF; ++cf) {
      float s = colS[cf], q = colQ[cf];
      s += __shfl_xor(s, 16); q += __shfl_xor(q, 16);
      s += __shfl_xor(s, 32); q += __shfl_xor(q, 32);
      if (lk == 0) {
        int col = colbase + cf * 16 + lr;
        atomicAdd(&stats[col], s);
        atomicAdd(&stats[D + col], q);
      }
    }
  }
}

// ---------------------------------------------------------------------------
// stats -> (scale, shift) for both node types
__global__ __launch_bounds__(256) void k_bnprep(const float* __restrict__ stats,
                                                const float* __restrict__ gamma,
                                                const float* __restrict__ beta,
                                                float* __restrict__ bnp0,
                                                float* __restrict__ bnp1,
                                                float invM0, float invM1) {
  int i = threadIdx.x;
  if (i < 128) {
    float mu = stats[i] * invM0;
    float var = stats[D + i] * invM0 - mu * mu;
    float sc = rsqrtf(var + BN_EPS) * gamma[i];
    bnp0[i] = sc;
    bnp0[D + i] = beta[i] - mu * sc;
  } else {
    int d = i - 128;
    float mu = stats[2 * D + d] * invM1;
    float var = stats[3 * D + d] * invM1 - mu * mu;
    float sc = rsqrtf(var + BN_EPS) * gamma[d];
    bnp1[d] = sc;
    bnp1[D + d] = beta[d] - mu * sc;
  }
}

// final-layer BN (no relu), fp32 in place
__global__ __launch_bounds__(256) void k_bnfin(float* __restrict__ X, int M,
                                               const float* __restrict__ bnp) {
  int idx = blockIdx.x * 256 + threadIdx.x;
  int i = idx >> 5, c4 = idx & 31;
  if (i >= M) return;
  float4 v = *(float4*)(X + (size_t)i * D + c4 * 4);
  float4 sc = *(const float4*)(bnp + c4 * 4);
  float4 sh = *(const float4*)(bnp + D + c4 * 4);
  float4 o;
  o.x = fmaf(v.x, sc.x, sh.x); o.y = fmaf(v.y, sc.y, sh.y);
  o.z = fmaf(v.z, sc.z, sh.z); o.w = fmaf(v.w, sc.w, sh.w);
  *(float4*)(X + (size_t)i * D + c4 * 4) = o;
}

// ---------------------------------------------------------------------------
extern "C" void kernel_launch(void* const* d_in, const int* in_sizes, int n_in,
                              void* d_out, int out_size, void* d_ws,
                              size_t ws_size, hipStream_t stream) {
  const int* x0 = (const int*)d_in[0];
  const int* x1 = (const int*)d_in[1];
  const int* ei101 = (const int*)d_in[2];
  const int* ea101 = (const int*)d_in[3];
  const int* ei110 = (const int*)d_in[4];
  const int* ea110 = (const int*)d_in[5];
  const int* ei021 = (const int*)d_in[6];
  const int* ea021 = (const int*)d_in[7];
  const int* ei030 = (const int*)d_in[8];
  const int* ea030 = (const int*)d_in[9];
  const float* x_emb1 = (const float*)d_in[10];
  const float* x_emb2 = (const float*)d_in[11];
  const float* e_emb1 = (const float*)d_in[12];
  const float* e_emb2 = (const float*)d_in[13];
  const float* gin_w1 = (const float*)d_in[14];
  const float* gin_b1 = (const float*)d_in[15];
  const float* gin_w2 = (const float*)d_in[16];
  const float* gin_b2 = (const float*)d_in[17];
  const float* w110 = (const float*)d_in[18];
  const float* b110 = (const float*)d_in[19];
  const float* w021 = (const float*)d_in[20];
  const float* b021 = (const float*)d_in[21];
  const float* w030 = (const float*)d_in[22];
  const float* b030 = (const float*)d_in[23];
  const float* bn_gamma = (const float*)d_in[24];
  const float* bn_beta = (const float*)d_in[25];

  int n0 = in_sizes[0] / 2, n1 = in_sizes[1] / 2;
  int E = in_sizes[2] / 2;
  int nmax = n0 > n1 ? n0 : n1;

  float* h0f = (float*)d_out;
  float* h1f = h0f + (size_t)n0 * D;

  // ---- workspace layout ----
  char* p = (char*)d_ws;
  auto alloc = [&](size_t bytes) {
    char* r = p;
    p += (bytes + 63) & ~(size_t)63;
    return r;
  };
  unsigned short* h0r = (unsigned short*)alloc((size_t)n0 * D * 2);
  unsigned short* h1r = (unsigned short*)alloc((size_t)n1 * D * 2);
  unsigned short* z1b = (unsigned short*)alloc((size_t)n1 * D * 2);
  unsigned short* a021b = (unsigned short*)alloc((size_t)n1 * D * 2);
  unsigned short* a110b = (unsigned short*)alloc((size_t)n0 * D * 2);
  unsigned short* a030b = (unsigned short*)alloc((size_t)n0 * D * 2);
  unsigned short* hiddenb = (unsigned short*)alloc((size_t)n1 * 256 * 2);
  float* etbl = (float*)alloc(10 * D * 4);
  float* stats = (float*)alloc(4 * D * 4);
  float* bnp0 = (float*)alloc(2 * D * 4);
  float* bnp1 = (float*)alloc(2 * D * 4);
  unsigned short* wt110 = (unsigned short*)alloc(128 * 128 * 2);
  unsigned short* wt030 = (unsigned short*)alloc(128 * 128 * 2);
  unsigned short* wt021 = (unsigned short*)alloc(128 * 128 * 2);
  unsigned short* wtg1 = (unsigned short*)alloc(256 * 128 * 2);  // [N=256][K=128]
  unsigned short* wtg2 = (unsigned short*)alloc(128 * 256 * 2);  // [N=128][K=256]
  float* bias0 = (float*)alloc(128 * 4);
  float* biash = (float*)alloc(256 * 4);
  float* bias1 = (float*)alloc(128 * 4);

  EdgeArr EA;
  CsrPtrs cp;
  const int* eis[4] = {ei101, ei021, ei110, ei030};
  const int* eas[4] = {ea101, ea021, ea110, ea030};
  int ndst[4] = {n1, n1, n0, n0};
  for (int t = 0; t < 4; ++t) {
    cp.rp[t] = (int*)alloc((size_t)(nmax + 1) * 4);
    cp.cur[t] = (int*)alloc((size_t)nmax * 4);
    EA.pay[t] = (int*)alloc((size_t)E * 4);
    cp.n[t] = ndst[t];
    EA.ei[t] = eis[t];
    EA.ea[t] = eas[t];
    EA.cur[t] = cp.cur[t];
  }
  int* bsum = (int*)alloc(4 * MAXNB * 4);

  dim3 b256(256);
  int eBlocks = (E + 255) / 256;

  // one-time: tables, embeddings, weight prep, CSR build
  k_etbl<<<5, b256, 0, stream>>>(e_emb1, e_emb2, etbl);
  k_embed<<<(n0 * 32 + 255) / 256, b256, 0, stream>>>(x0, x_emb1, x_emb2, h0r, n0);
  k_embed<<<(n1 * 32 + 255) / 256, b256, 0, stream>>>(x1, x_emb1, x_emb2, h1r, n1);
  k_wprep<<<64, b256, 0, stream>>>(w110, wt110, 128, 128, 0.05f);
  k_wprep<<<64, b256, 0, stream>>>(w030, wt030, 128, 128, 0.05f);
  k_wprep<<<64, b256, 0, stream>>>(w021, wt021, 128, 128, 0.05f);
  k_wprep<<<128, b256, 0, stream>>>(gin_w1, wtg1, 128, 256, 1.0f);
  k_wprep<<<128, b256, 0, stream>>>(gin_w2, wtg2, 256, 128, 0.5f);
  k_bprep<<<1, b256, 0, stream>>>(b110, b030, gin_b1, gin_b2, b021, bias0, biash, bias1);

  for (int t = 0; t < 4; ++t)
    hipMemsetAsync(cp.cur[t], 0, (size_t)ndst[t] * sizeof(int), stream);
  k_hist4<<<dim3(eBlocks, 4), b256, 0, stream>>>(EA, E);
  hipMemsetAsync(bsum, 0, 4 * MAXNB * sizeof(int), stream);
  int nb = (nmax + 4095) / 4096;
  k_scan1<<<dim3(nb, 4), b256, 0, stream>>>(cp, bsum);
  k_scan2<<<1, dim3(64), 0, stream>>>(bsum);
  k_scan3<<<dim3(nb, 4), b256, 0, stream>>>(cp, bsum, E);
  k_fill4<<<dim3(eBlocks, 4), b256, 0, stream>>>(EA, E);

  int gB0 = (n0 + 7) / 8, gB1 = (n1 + 7) / 8;
  int mB0 = (n0 + 63) / 64, mB1 = (n1 + 63) / 64;

  for (int layer = 0; layer < 3; ++layer) {
    // aggregations: BN+ReLU of h folded into the read (layers 1,2)
    if (layer == 0) {
      k_gather<2, false><<<gB1, b256, 0, stream>>>(h1r, h1r, cp.rp[0], EA.pay[0], etbl, nullptr, z1b, n1);
      k_gather<0, false><<<gB1, b256, 0, stream>>>(h0r, nullptr, cp.rp[1], EA.pay[1], etbl, nullptr, a021b, n1);
      k_gather<0, false><<<gB0, b256, 0, stream>>>(h1r, nullptr, cp.rp[2], EA.pay[2], etbl, nullptr, a110b, n0);
      k_gather<1, false><<<gB0, b256, 0, stream>>>(h0r, h0r, cp.rp[3], EA.pay[3], etbl, nullptr, a030b, n0);
    } else {
      k_gather<2, true><<<gB1, b256, 0, stream>>>(h1r, h1r, cp.rp[0], EA.pay[0], etbl, bnp1, z1b, n1);
      k_gather<0, true><<<gB1, b256, 0, stream>>>(h0r, nullptr, cp.rp[1], EA.pay[1], etbl, bnp0, a021b, n1);
      k_gather<0, true><<<gB0, b256, 0, stream>>>(h1r, nullptr, cp.rp[2], EA.pay[2], etbl, bnp1, a110b, n0);
      k_gather<1, true><<<gB0, b256, 0, stream>>>(h0r, h0r, cp.rp[3], EA.pay[3], etbl, bnp0, a030b, n0);
    }

    hipMemsetAsync(stats, 0, 4 * D * sizeof(float), stream);

    if (layer < 2) {
      // raw (pre-BN) bf16 outputs into h0r/h1r
      gemm_breg<128, 128, 128, false, true, true><<<mB0, b256, 0, stream>>>(
          a110b, wt110, a030b, wt030, bias0, h0r, n0, stats);
      gemm_breg<256, 128, 0, true, false, true><<<mB1, b256, 0, stream>>>(
          z1b, wtg1, nullptr, nullptr, biash, hiddenb, n1, nullptr);
      gemm_breg<128, 256, 128, false, true, true><<<mB1, b256, 0, stream>>>(
          hiddenb, wtg2, a021b, wt021, bias1, h1r, n1, stats + 2 * D);
    } else {
      // final layer: raw fp32 straight into d_out, BN applied in place after
      gemm_breg<128, 128, 128, false, true, false><<<mB0, b256, 0, stream>>>(
          a110b, wt110, a030b, wt030, bias0, h0f, n0, stats);
      gemm_breg<256, 128, 0, true, false, true><<<mB1, b256, 0, stream>>>(
          z1b, wtg1, nullptr, nullptr, biash, hiddenb, n1, nullptr);
      gemm_breg<128, 256, 128, false, true, false><<<mB1, b256, 0, stream>>>(
          hiddenb, wtg2, a021b, wt021, bias1, h1f, n1, stats + 2 * D);
    }

    k_bnprep<<<1, b256, 0, stream>>>(stats, bn_gamma + layer * D,
                                     bn_beta + layer * D, bnp0, bnp1,
                                     1.0f / n0, 1.0f / n1);
    if (layer == 2) {
      k_bnfin<<<(n0 * 32 + 255) / 256, b256, 0, stream>>>(h0f, n0, bnp0);
      k_bnfin<<<(n1 * 32 + 255) / 256, b256, 0, stream>>>(h1f, n1, bnp1);
    }
  }
}

// Round 8
// 780.221 us; speedup vs baseline: 9.6749x; 1.0215x over previous
//
#include <hip/hip_runtime.h>

#define D 128
#define BN_EPS 1e-5f
#define MAXNB 16  // max scan blocks per type (n <= 65536)

typedef __attribute__((ext_vector_type(8))) short bf16x8;
typedef __attribute__((ext_vector_type(4))) float f32x4;

__device__ __forceinline__ unsigned short f2bf(float x) {
  unsigned u = __float_as_uint(x);
  u += 0x7FFF + ((u >> 16) & 1);  // round-to-nearest-even
  return (unsigned short)(u >> 16);
}
__device__ __forceinline__ float bf2f(unsigned short u) {
  return __uint_as_float((unsigned)u << 16);
}

// ---------------------------------------------------------------------------
// edge-attr combo table: 9 combos + self-loop (4,0) at slot 9
__global__ __launch_bounds__(256) void k_etbl(const float* __restrict__ e1,
                                              const float* __restrict__ e2,
                                              float* __restrict__ etbl) {
  int idx = blockIdx.x * 256 + threadIdx.x;
  if (idx < 9 * D) {
    int combo = idx / D, c = idx % D;
    etbl[idx] = e1[(combo / 3) * D + c] + e2[(combo % 3) * D + c];
  } else if (idx < 10 * D) {
    int c = idx - 9 * D;
    etbl[idx] = e1[4 * D + c] + e2[c];
  }
}

// node embedding -> bf16 h
__global__ __launch_bounds__(256) void k_embed(const int* __restrict__ x,
                                               const float* __restrict__ emb1,
                                               const float* __restrict__ emb2,
                                               unsigned short* __restrict__ out,
                                               int n) {
  int idx = blockIdx.x * 256 + threadIdx.x;
  if (idx >= n * 32) return;
  int node = idx >> 5, c4 = idx & 31;
  int i1 = x[2 * node], i2 = x[2 * node + 1];
  float4 v1 = *(const float4*)(emb1 + (size_t)i1 * D + c4 * 4);
  float4 v2 = *(const float4*)(emb2 + (size_t)i2 * D + c4 * 4);
  ushort4 o;
  o.x = f2bf(v1.x + v2.x); o.y = f2bf(v1.y + v2.y);
  o.z = f2bf(v1.z + v2.z); o.w = f2bf(v1.w + v2.w);
  *(ushort4*)(out + (size_t)node * D + c4 * 4) = o;
}

// ---------------------------------------------------------------------------
// weight prep: Wt[n][k] = bf16(W[k][n] * scale)
__global__ __launch_bounds__(256) void k_wprep(const float* __restrict__ W,
                                               unsigned short* __restrict__ Wt,
                                               int K, int N, float scale) {
  int idx = blockIdx.x * 256 + threadIdx.x;
  if (idx >= K * N) return;
  int n = idx / K, k = idx - n * K;
  Wt[idx] = f2bf(W[(size_t)k * N + n] * scale);
}

__global__ __launch_bounds__(256) void k_bprep(
    const float* __restrict__ b110, const float* __restrict__ b030,
    const float* __restrict__ gb1, const float* __restrict__ gb2,
    const float* __restrict__ b021, float* __restrict__ bias0,
    float* __restrict__ biash, float* __restrict__ bias1) {
  int i = threadIdx.x;
  if (i < 128) {
    bias0[i] = 0.05f * (b110[i] + b030[i]);
    bias1[i] = 0.5f * gb2[i] + 0.05f * b021[i];
  }
  biash[i] = gb1[i];
}

// ---------------------------------------------------------------------------
// CSR build (all 4 edge types via grid.y)
struct EdgeArr {
  const int* ei[4];
  const int* ea[4];
  int* cur[4];
  int* pay[4];
};
struct CsrPtrs {
  int* cur[4];
  int* rp[4];
  int n[4];
};

__global__ __launch_bounds__(256) void k_hist4(EdgeArr A, int E) {
  int t = blockIdx.y;
  int e = blockIdx.x * 256 + threadIdx.x;
  if (e >= E) return;
  atomicAdd(&A.cur[t][A.ei[t][E + e]], 1);
}

__global__ __launch_bounds__(256) void k_scan1(CsrPtrs p, int* __restrict__ bsum) {
  __shared__ int lds[256];
  int type = blockIdx.y;
  const int* cur = p.cur[type];
  int n = p.n[type];
  int base = blockIdx.x * 4096;
  int s = 0;
  for (int i = threadIdx.x; i < 4096; i += 256) {
    int idx = base + i;
    if (idx < n) s += cur[idx];
  }
  int tid = threadIdx.x;
  lds[tid] = s;
  __syncthreads();
  for (int off = 128; off > 0; off >>= 1) {
    if (tid < off) lds[tid] += lds[tid + off];
    __syncthreads();
  }
  if (tid == 0) bsum[type * MAXNB + blockIdx.x] = lds[0];
}

__global__ __launch_bounds__(64) void k_scan2(int* __restrict__ bsum) {
  int t = threadIdx.x;
  if (t < 4) {
    int run = 0;
    for (int i = 0; i < MAXNB; ++i) {
      int v = bsum[t * MAXNB + i];
      bsum[t * MAXNB + i] = run;
      run += v;
    }
  }
}

__global__ __launch_bounds__(256) void k_scan3(CsrPtrs p,
                                               const int* __restrict__ bsum,
                                               int E) {
  __shared__ int lds[256];
  int type = blockIdx.y;
  int* cur = p.cur[type];
  int* rp = p.rp[type];
  int n = p.n[type];
  int tid = threadIdx.x;
  if (blockIdx.x == 0 && tid == 0) rp[n] = E;
  int t0 = blockIdx.x * 4096 + tid * 16;
  int loc[16];
  int s = 0;
#pragma unroll
  for (int j = 0; j < 16; ++j) {
    int idx = t0 + j;
    int v = (idx < n) ? cur[idx] : 0;
    loc[j] = s;
    s += v;
  }
  lds[tid] = s;
  __syncthreads();
  for (int off = 1; off < 256; off <<= 1) {
    int v = (tid >= off) ? lds[tid - off] : 0;
    __syncthreads();
    lds[tid] += v;
    __syncthreads();
  }
  int off0 = bsum[type * MAXNB + blockIdx.x] + ((tid == 0) ? 0 : lds[tid - 1]);
#pragma unroll
  for (int j = 0; j < 16; ++j) {
    int idx = t0 + j;
    if (idx < n) {
      int v = off0 + loc[j];
      rp[idx] = v;
      cur[idx] = v;  // cursor becomes fill position
    }
  }
}

// payload = src | (combo << 16)
__global__ __launch_bounds__(256) void k_fill4(EdgeArr A, int E) {
  int t = blockIdx.y;
  int e = blockIdx.x * 256 + threadIdx.x;
  if (e >= E) return;
  const int* ei = A.ei[t];
  const int* ea = A.ea[t];
  int dst = ei[E + e];
  int src = ei[e];
  int combo = ea[2 * e] * 3 + ea[2 * e + 1];
  int pos = atomicAdd(&A.cur[t][dst], 1);
  A.pay[t][pos] = src | (combo << 16);
}

// ---------------------------------------------------------------------------
// Merged CSR gather: all 4 edge types in one dispatch (grid.y = type).
// 16 lanes/node, bf16x8 (16B) loads, 4-deep unrolled edge loop for MLP.
// mode: 0: init=0; 1: init=h~(g)+es; 2: init=2.1*h~(g)+es
// norm: h~ = relu(h*sc+sh) applied on read (layers 1,2), else h~ = h.
struct GArgs {
  const unsigned short* src[4];
  const unsigned short* ini[4];
  const float* bnp[4];
  const int* rp[4];
  const int* pay[4];
  unsigned short* agg[4];
  int mode[4];
  int n[4];
  int norm;
};

__device__ __forceinline__ void cvt8(float (&f)[8], bf16x8 r) {
  const unsigned* u = (const unsigned*)&r;
#pragma unroll
  for (int j = 0; j < 4; ++j) {
    f[2 * j] = __uint_as_float(u[j] << 16);
    f[2 * j + 1] = __uint_as_float(u[j] & 0xFFFF0000u);
  }
}

__device__ __forceinline__ void addrow(float (&acc)[8], bf16x8 r,
                                       const float* etp, const float (&sc)[8],
                                       const float (&sh)[8], bool norm) {
  float f[8];
  cvt8(f, r);
  if (norm) {
#pragma unroll
    for (int j = 0; j < 8; ++j) f[j] = fmaxf(fmaf(f[j], sc[j], sh[j]), 0.f);
  }
  float4 ea = *(const float4*)etp;
  float4 eb = *(const float4*)(etp + 4);
  acc[0] += f[0] + ea.x; acc[1] += f[1] + ea.y;
  acc[2] += f[2] + ea.z; acc[3] += f[3] + ea.w;
  acc[4] += f[4] + eb.x; acc[5] += f[5] + eb.y;
  acc[6] += f[6] + eb.z; acc[7] += f[7] + eb.w;
}

__global__ __launch_bounds__(256) void k_gather_all(GArgs G,
                                                    const float* __restrict__ etbl) {
  __shared__ float et[10 * D];
  for (int i = threadIdx.x; i < 10 * D; i += 256) et[i] = etbl[i];
  __syncthreads();
  int t = blockIdx.y;
  int g = blockIdx.x * 16 + (threadIdx.x >> 4);
  if (g >= G.n[t]) return;
  int l = threadIdx.x & 15;
  int c = l * 8;
  const unsigned short* __restrict__ hsrc = G.src[t];
  const int* __restrict__ pay = G.pay[t];
  bool norm = G.norm != 0;

  float sc[8], sh[8];
  if (norm) {
    const float* bnp = G.bnp[t];
#pragma unroll
    for (int j = 0; j < 8; ++j) { sc[j] = bnp[c + j]; sh[j] = bnp[D + c + j]; }
  } else {
#pragma unroll
    for (int j = 0; j < 8; ++j) { sc[j] = 1.f; sh[j] = 0.f; }
  }

  float acc[8];
  int mode = G.mode[t];
  if (mode == 0) {
#pragma unroll
    for (int j = 0; j < 8; ++j) acc[j] = 0.f;
  } else {
    bf16x8 hv = *(const bf16x8*)(G.ini[t] + (size_t)g * D + c);
    float f[8];
    cvt8(f, hv);
    if (norm) {
#pragma unroll
      for (int j = 0; j < 8; ++j) f[j] = fmaxf(fmaf(f[j], sc[j], sh[j]), 0.f);
    }
    float m = (mode == 2) ? 2.1f : 1.0f;
#pragma unroll
    for (int j = 0; j < 8; ++j) acc[j] = m * f[j] + et[9 * D + c + j];
  }

  int e0 = G.rp[t][g], e1 = G.rp[t][g + 1];
  int e = e0;
  while (e < e1) {
    int cnt = min(16, e1 - e);
    int pv = (e + l < e1) ? pay[e + l] : 0;  // coalesced 16-edge chunk
    int j = 0;
    for (; j + 3 < cnt; j += 4) {
      int p0 = __shfl(pv, j, 16);
      int p1 = __shfl(pv, j + 1, 16);
      int p2 = __shfl(pv, j + 2, 16);
      int p3 = __shfl(pv, j + 3, 16);
      bf16x8 r0 = *(const bf16x8*)(hsrc + (size_t)(p0 & 0xFFFF) * D + c);
      bf16x8 r1 = *(const bf16x8*)(hsrc + (size_t)(p1 & 0xFFFF) * D + c);
      bf16x8 r2 = *(const bf16x8*)(hsrc + (size_t)(p2 & 0xFFFF) * D + c);
      bf16x8 r3 = *(const bf16x8*)(hsrc + (size_t)(p3 & 0xFFFF) * D + c);
      addrow(acc, r0, et + (p0 >> 16) * D + c, sc, sh, norm);
      addrow(acc, r1, et + (p1 >> 16) * D + c, sc, sh, norm);
      addrow(acc, r2, et + (p2 >> 16) * D + c, sc, sh, norm);
      addrow(acc, r3, et + (p3 >> 16) * D + c, sc, sh, norm);
    }
    for (; j < cnt; ++j) {
      int p0 = __shfl(pv, j, 16);
      bf16x8 r0 = *(const bf16x8*)(hsrc + (size_t)(p0 & 0xFFFF) * D + c);
      addrow(acc, r0, et + (p0 >> 16) * D + c, sc, sh, norm);
    }
    e += cnt;
  }

  unsigned o0 = (unsigned)f2bf(acc[0]) | ((unsigned)f2bf(acc[1]) << 16);
  unsigned o1 = (unsigned)f2bf(acc[2]) | ((unsigned)f2bf(acc[3]) << 16);
  unsigned o2 = (unsigned)f2bf(acc[4]) | ((unsigned)f2bf(acc[5]) << 16);
  unsigned o3 = (unsigned)f2bf(acc[6]) | ((unsigned)f2bf(acc[7]) << 16);
  *(uint4*)(G.agg[t] + (size_t)g * D + c) = make_uint4(o0, o1, o2, o3);
}

// ---------------------------------------------------------------------------
// B-stationary bf16 MFMA GEMM (unchanged from round 7).
template <int NCOLS, int K1, int K2, bool RELU, bool STATS, bool OBF16>
__global__ __launch_bounds__(256) void gemm_breg(
    const unsigned short* __restrict__ A1, const unsigned short* __restrict__ Wt1,
    const unsigned short* __restrict__ A2, const unsigned short* __restrict__ Wt2,
    const float* __restrict__ bias, void* __restrict__ Cv, int M,
    float* __restrict__ stats) {
  constexpr int WC = NCOLS / 4;
  constexpr int CF = WC / 16;
  constexpr int KF1 = K1 / 32;
  constexpr int KF2 = (K2 > 0) ? (K2 / 32) : 1;

  int tid = threadIdx.x;
  int w = tid >> 6, l = tid & 63;
  int lr = l & 15, lk = l >> 4;
  int colbase = w * WC;
  int row0 = blockIdx.x * 64;

  f32x4 acc[4][CF];
#pragma unroll
  for (int rf = 0; rf < 4; ++rf)
#pragma unroll
    for (int cf = 0; cf < CF; ++cf) acc[rf][cf] = (f32x4)(0.f);

  {
    const unsigned short* ap[4];
#pragma unroll
    for (int rf = 0; rf < 4; ++rf) {
      int r = row0 + rf * 16 + lr;
      if (r > M - 1) r = M - 1;
      ap[rf] = A1 + (size_t)r * K1 + lk * 8;
    }
    bf16x8 B[CF][KF1];
#pragma unroll
    for (int cf = 0; cf < CF; ++cf)
#pragma unroll
      for (int kf = 0; kf < KF1; ++kf)
        B[cf][kf] = *(const bf16x8*)(Wt1 + (size_t)(colbase + cf * 16 + lr) * K1 +
                                     kf * 32 + lk * 8);
#pragma unroll
    for (int kf = 0; kf < KF1; ++kf) {
      bf16x8 a[4];
#pragma unroll
      for (int rf = 0; rf < 4; ++rf) a[rf] = *(const bf16x8*)(ap[rf] + kf * 32);
#pragma unroll
      for (int rf = 0; rf < 4; ++rf)
#pragma unroll
        for (int cf = 0; cf < CF; ++cf)
          acc[rf][cf] = __builtin_amdgcn_mfma_f32_16x16x32_bf16(a[rf], B[cf][kf],
                                                                acc[rf][cf], 0, 0, 0);
    }
  }
  if constexpr (K2 > 0) {
    const unsigned short* ap[4];
#pragma unroll
    for (int rf = 0; rf < 4; ++rf) {
      int r = row0 + rf * 16 + lr;
      if (r > M - 1) r = M - 1;
      ap[rf] = A2 + (size_t)r * K2 + lk * 8;
    }
    bf16x8 B[CF][KF2];
#pragma unroll
    for (int cf = 0; cf < CF; ++cf)
#pragma unroll
      for (int kf = 0; kf < KF2; ++kf)
        B[cf][kf] = *(const bf16x8*)(Wt2 + (size_t)(colbase + cf * 16 + lr) * K2 +
                                     kf * 32 + lk * 8);
#pragma unroll
    for (int kf = 0; kf < KF2; ++kf) {
      bf16x8 a[4];
#pragma unroll
      for (int rf = 0; rf < 4; ++rf) a[rf] = *(const bf16x8*)(ap[rf] + kf * 32);
#pragma unroll
      for (int rf = 0; rf < 4; ++rf)
#pragma unroll
        for (int cf = 0; cf < CF; ++cf)
          acc[rf][cf] = __builtin_amdgcn_mfma_f32_16x16x32_bf16(a[rf], B[cf][kf],
                                                                acc[rf][cf], 0, 0, 0);
    }
  }

  float bv[CF];
#pragma unroll
  for (int cf = 0; cf < CF; ++cf) bv[cf] = bias[colbase + cf * 16 + lr];

  float colS[CF], colQ[CF];
#pragma unroll
  for (int cf = 0; cf < CF; ++cf) { colS[cf] = 0.f; colQ[cf] = 0.f; }

  float* Cf = (float*)Cv;
  unsigned short* Cb = (unsigned short*)Cv;
#pragma unroll
  for (int rf = 0; rf < 4; ++rf) {
#pragma unroll
    for (int r = 0; r < 4; ++r) {
      int row = row0 + rf * 16 + lk * 4 + r;
      bool ok = row < M;
#pragma unroll
      for (int cf = 0; cf < CF; ++cf) {
        int col = colbase + cf * 16 + lr;
        float v = acc[rf][cf][r] + bv[cf];
        if (RELU) v = fmaxf(v, 0.f);
        if (ok) {
          if (OBF16)
            Cb[(size_t)row * NCOLS + col] = f2bf(v);
          else
            Cf[(size_t)row * NCOLS + col] = v;
          if (STATS) { colS[cf] += v; colQ[cf] += v * v; }
        }
      }
    }
  }

  if constexpr (STATS) {
#pragma unroll
    for (int cf = 0; cf < CF; ++cf) {
      float s = colS[cf], q = colQ[cf];
      s += __shfl_xor(s, 16); q += __shfl_xor(q, 16);
      s += __shfl_xor(s, 32); q += __shfl_xor(q, 32);
      if (lk == 0) {
        int col = colbase + cf * 16 + lr;
        atomicAdd(&stats[col], s);
        atomicAdd(&stats[D + col], q);
      }
    }
  }
}

// ---------------------------------------------------------------------------
__global__ __launch_bounds__(256) void k_bnprep(const float* __restrict__ stats,
                                                const float* __restrict__ gamma,
                                                const float* __restrict__ beta,
                                                float* __restrict__ bnp0,
                                                float* __restrict__ bnp1,
                                                float invM0, float invM1) {
  int i = threadIdx.x;
  if (i < 128) {
    float mu = stats[i] * invM0;
    float var = stats[D + i] * invM0 - mu * mu;
    float sc = rsqrtf(var + BN_EPS) * gamma[i];
    bnp0[i] = sc;
    bnp0[D + i] = beta[i] - mu * sc;
  } else {
    int d = i - 128;
    float mu = stats[2 * D + d] * invM1;
    float var = stats[3 * D + d] * invM1 - mu * mu;
    float sc = rsqrtf(var + BN_EPS) * gamma[d];
    bnp1[d] = sc;
    bnp1[D + d] = beta[d] - mu * sc;
  }
}

// final-layer BN (no relu), fp32 in place
__global__ __launch_bounds__(256) void k_bnfin(float* __restrict__ X, int M,
                                               const float* __restrict__ bnp) {
  int idx = blockIdx.x * 256 + threadIdx.x;
  int i = idx >> 5, c4 = idx & 31;
  if (i >= M) return;
  float4 v = *(float4*)(X + (size_t)i * D + c4 * 4);
  float4 sc = *(const float4*)(bnp + c4 * 4);
  float4 sh = *(const float4*)(bnp + D + c4 * 4);
  float4 o;
  o.x = fmaf(v.x, sc.x, sh.x); o.y = fmaf(v.y, sc.y, sh.y);
  o.z = fmaf(v.z, sc.z, sh.z); o.w = fmaf(v.w, sc.w, sh.w);
  *(float4*)(X + (size_t)i * D + c4 * 4) = o;
}

// ---------------------------------------------------------------------------
extern "C" void kernel_launch(void* const* d_in, const int* in_sizes, int n_in,
                              void* d_out, int out_size, void* d_ws,
                              size_t ws_size, hipStream_t stream) {
  const int* x0 = (const int*)d_in[0];
  const int* x1 = (const int*)d_in[1];
  const int* ei101 = (const int*)d_in[2];
  const int* ea101 = (const int*)d_in[3];
  const int* ei110 = (const int*)d_in[4];
  const int* ea110 = (const int*)d_in[5];
  const int* ei021 = (const int*)d_in[6];
  const int* ea021 = (const int*)d_in[7];
  const int* ei030 = (const int*)d_in[8];
  const int* ea030 = (const int*)d_in[9];
  const float* x_emb1 = (const float*)d_in[10];
  const float* x_emb2 = (const float*)d_in[11];
  const float* e_emb1 = (const float*)d_in[12];
  const float* e_emb2 = (const float*)d_in[13];
  const float* gin_w1 = (const float*)d_in[14];
  const float* gin_b1 = (const float*)d_in[15];
  const float* gin_w2 = (const float*)d_in[16];
  const float* gin_b2 = (const float*)d_in[17];
  const float* w110 = (const float*)d_in[18];
  const float* b110 = (const float*)d_in[19];
  const float* w021 = (const float*)d_in[20];
  const float* b021 = (const float*)d_in[21];
  const float* w030 = (const float*)d_in[22];
  const float* b030 = (const float*)d_in[23];
  const float* bn_gamma = (const float*)d_in[24];
  const float* bn_beta = (const float*)d_in[25];

  int n0 = in_sizes[0] / 2, n1 = in_sizes[1] / 2;
  int E = in_sizes[2] / 2;
  int nmax = n0 > n1 ? n0 : n1;

  float* h0f = (float*)d_out;
  float* h1f = h0f + (size_t)n0 * D;

  // ---- workspace layout ----
  char* p = (char*)d_ws;
  auto alloc = [&](size_t bytes) {
    char* r = p;
    p += (bytes + 63) & ~(size_t)63;
    return r;
  };
  unsigned short* h0r = (unsigned short*)alloc((size_t)n0 * D * 2);
  unsigned short* h1r = (unsigned short*)alloc((size_t)n1 * D * 2);
  unsigned short* z1b = (unsigned short*)alloc((size_t)n1 * D * 2);
  unsigned short* a021b = (unsigned short*)alloc((size_t)n1 * D * 2);
  unsigned short* a110b = (unsigned short*)alloc((size_t)n0 * D * 2);
  unsigned short* a030b = (unsigned short*)alloc((size_t)n0 * D * 2);
  unsigned short* hiddenb = (unsigned short*)alloc((size_t)n1 * 256 * 2);
  float* etbl = (float*)alloc(10 * D * 4);
  float* stats = (float*)alloc(4 * D * 4);
  float* bnp0 = (float*)alloc(2 * D * 4);
  float* bnp1 = (float*)alloc(2 * D * 4);
  unsigned short* wt110 = (unsigned short*)alloc(128 * 128 * 2);
  unsigned short* wt030 = (unsigned short*)alloc(128 * 128 * 2);
  unsigned short* wt021 = (unsigned short*)alloc(128 * 128 * 2);
  unsigned short* wtg1 = (unsigned short*)alloc(256 * 128 * 2);  // [N=256][K=128]
  unsigned short* wtg2 = (unsigned short*)alloc(128 * 256 * 2);  // [N=128][K=256]
  float* bias0 = (float*)alloc(128 * 4);
  float* biash = (float*)alloc(256 * 4);
  float* bias1 = (float*)alloc(128 * 4);

  EdgeArr EA;
  CsrPtrs cp;
  const int* eis[4] = {ei101, ei021, ei110, ei030};
  const int* eas[4] = {ea101, ea021, ea110, ea030};
  int ndst[4] = {n1, n1, n0, n0};
  for (int t = 0; t < 4; ++t) {
    cp.rp[t] = (int*)alloc((size_t)(nmax + 1) * 4);
    cp.cur[t] = (int*)alloc((size_t)nmax * 4);
    EA.pay[t] = (int*)alloc((size_t)E * 4);
    cp.n[t] = ndst[t];
    EA.ei[t] = eis[t];
    EA.ea[t] = eas[t];
    EA.cur[t] = cp.cur[t];
  }
  int* bsum = (int*)alloc(4 * MAXNB * 4);

  dim3 b256(256);
  int eBlocks = (E + 255) / 256;

  // one-time: tables, embeddings, weight prep, CSR build
  k_etbl<<<5, b256, 0, stream>>>(e_emb1, e_emb2, etbl);
  k_embed<<<(n0 * 32 + 255) / 256, b256, 0, stream>>>(x0, x_emb1, x_emb2, h0r, n0);
  k_embed<<<(n1 * 32 + 255) / 256, b256, 0, stream>>>(x1, x_emb1, x_emb2, h1r, n1);
  k_wprep<<<64, b256, 0, stream>>>(w110, wt110, 128, 128, 0.05f);
  k_wprep<<<64, b256, 0, stream>>>(w030, wt030, 128, 128, 0.05f);
  k_wprep<<<64, b256, 0, stream>>>(w021, wt021, 128, 128, 0.05f);
  k_wprep<<<128, b256, 0, stream>>>(gin_w1, wtg1, 128, 256, 1.0f);
  k_wprep<<<128, b256, 0, stream>>>(gin_w2, wtg2, 256, 128, 0.5f);
  k_bprep<<<1, b256, 0, stream>>>(b110, b030, gin_b1, gin_b2, b021, bias0, biash, bias1);

  for (int t = 0; t < 4; ++t)
    hipMemsetAsync(cp.cur[t], 0, (size_t)ndst[t] * sizeof(int), stream);
  k_hist4<<<dim3(eBlocks, 4), b256, 0, stream>>>(EA, E);
  hipMemsetAsync(bsum, 0, 4 * MAXNB * sizeof(int), stream);
  int nb = (nmax + 4095) / 4096;
  k_scan1<<<dim3(nb, 4), b256, 0, stream>>>(cp, bsum);
  k_scan2<<<1, dim3(64), 0, stream>>>(bsum);
  k_scan3<<<dim3(nb, 4), b256, 0, stream>>>(cp, bsum, E);
  k_fill4<<<dim3(eBlocks, 4), b256, 0, stream>>>(EA, E);

  // merged gather args (types: z1, a021, a110, a030)
  GArgs GA;
  GA.src[0] = h1r; GA.ini[0] = h1r;     GA.bnp[0] = bnp1; GA.agg[0] = z1b;   GA.mode[0] = 2; GA.n[0] = n1;
  GA.src[1] = h0r; GA.ini[1] = nullptr; GA.bnp[1] = bnp0; GA.agg[1] = a021b; GA.mode[1] = 0; GA.n[1] = n1;
  GA.src[2] = h1r; GA.ini[2] = nullptr; GA.bnp[2] = bnp1; GA.agg[2] = a110b; GA.mode[2] = 0; GA.n[2] = n0;
  GA.src[3] = h0r; GA.ini[3] = h0r;     GA.bnp[3] = bnp0; GA.agg[3] = a030b; GA.mode[3] = 1; GA.n[3] = n0;
  for (int t = 0; t < 4; ++t) {
    GA.rp[t] = cp.rp[t];
    GA.pay[t] = EA.pay[t];
  }

  int mB0 = (n0 + 63) / 64, mB1 = (n1 + 63) / 64;
  dim3 gGrid((nmax + 15) / 16, 4);

  for (int layer = 0; layer < 3; ++layer) {
    GA.norm = (layer > 0) ? 1 : 0;
    k_gather_all<<<gGrid, b256, 0, stream>>>(GA, etbl);

    hipMemsetAsync(stats, 0, 4 * D * sizeof(float), stream);

    if (layer < 2) {
      // raw (pre-BN) bf16 outputs into h0r/h1r
      gemm_breg<128, 128, 128, false, true, true><<<mB0, b256, 0, stream>>>(
          a110b, wt110, a030b, wt030, bias0, h0r, n0, stats);
      gemm_breg<256, 128, 0, true, false, true><<<mB1, b256, 0, stream>>>(
          z1b, wtg1, nullptr, nullptr, biash, hiddenb, n1, nullptr);
      gemm_breg<128, 256, 128, false, true, true><<<mB1, b256, 0, stream>>>(
          hiddenb, wtg2, a021b, wt021, bias1, h1r, n1, stats + 2 * D);
    } else {
      // final layer: raw fp32 straight into d_out, BN applied in place after
      gemm_breg<128, 128, 128, false, true, false><<<mB0, b256, 0, stream>>>(
          a110b, wt110, a030b, wt030, bias0, h0f, n0, stats);
      gemm_breg<256, 128, 0, true, false, true><<<mB1, b256, 0, stream>>>(
          z1b, wtg1, nullptr, nullptr, biash, hiddenb, n1, nullptr);
      gemm_breg<128, 256, 128, false, true, false><<<mB1, b256, 0, stream>>>(
          hiddenb, wtg2, a021b, wt021, bias1, h1f, n1, stats + 2 * D);
    }

    k_bnprep<<<1, b256, 0, stream>>>(stats, bn_gamma + layer * D,
                                     bn_beta + layer * D, bnp0, bnp1,
                                     1.0f / n0, 1.0f / n1);
    if (layer == 2) {
      k_bnfin<<<(n0 * 32 + 255) / 256, b256, 0, stream>>>(h0f, n0, bnp0);
      k_bnfin<<<(n1 * 32 + 255) / 256, b256, 0, stream>>>(h1f, n1, bnp1);
    }
  }
}